// Round 4
// baseline (777.555 us; speedup 1.0000x reference)
//
#include <hip/hip_runtime.h>

#define BSZ_  4
#define SEQ_  1024
#define NH_   32
#define NKVH_ 8
#define HD_   128
#define DIM_  4096
#define NTOK_ (BSZ_ * SEQ_)   // 4096 tokens
#define QKVW_ 6144            // fused QKV output width (u16 elems per token)

typedef float  floatx4  __attribute__((ext_vector_type(4)));
typedef float  floatx16 __attribute__((ext_vector_type(16)));
typedef __bf16 bf16x8   __attribute__((ext_vector_type(8)));
typedef unsigned short ushortx8 __attribute__((ext_vector_type(8)));

__device__ __forceinline__ float fast_exp2(float x) {
  return __builtin_amdgcn_exp2f(x);   // v_exp_f32 (computes 2^x natively)
}

__device__ __forceinline__ unsigned short f2bf_bits(float f) {
  unsigned int u = __float_as_uint(f);
  u += 0x7FFFu + ((u >> 16) & 1u);   // round-to-nearest-even
  return (unsigned short)(u >> 16);
}
__device__ __forceinline__ unsigned int pack_bf2_rne(float lo, float hi_) {
  return (unsigned int)f2bf_bits(lo) | ((unsigned int)f2bf_bits(hi_) << 16);
}
// truncating pack of two fp32 -> bf16x2 (one v_perm_b32)
__device__ __forceinline__ unsigned int pack_bf2_trunc(float lo, float hi_) {
  return __builtin_amdgcn_perm(__float_as_uint(hi_), __float_as_uint(lo), 0x07060302u);
}

// async global->LDS, 16B per lane; LDS dest = wave-uniform base + lane*16
__device__ __forceinline__ void gld16(const void* g, void* l) {
  __builtin_amdgcn_global_load_lds(
      (const __attribute__((address_space(1))) void*)g,
      (__attribute__((address_space(3))) void*)l, 16, 0, 0);
}

// ---------------------------------------------------------------------------
// fp32 -> bf16 convert (contiguous).
// ---------------------------------------------------------------------------
__global__ __launch_bounds__(256)
void xconv(const float* __restrict__ X, unsigned short* __restrict__ XB)
{
  size_t i = ((size_t)blockIdx.x * 256 + threadIdx.x) * 4;
  float4 v = *(const float4*)&X[i];
  ushort4 o;
  o.x = f2bf_bits(v.x); o.y = f2bf_bits(v.y);
  o.z = f2bf_bits(v.z); o.w = f2bf_bits(v.w);
  *(ushort4*)&XB[i] = o;
}

// ---------------------------------------------------------------------------
// Weight transpose-convert: W[K][N] fp32 -> WT[N][K] bf16. 32x32 tiles.
// ---------------------------------------------------------------------------
__global__ __launch_bounds__(256)
void wtrans(const float* __restrict__ W, unsigned short* __restrict__ WT,
            int K, int N)
{
  __shared__ unsigned short T[32][36];
  const int k0 = blockIdx.y * 32, n0 = blockIdx.x * 32;
  const int t = threadIdx.x;
  {
    int kr = t >> 3, nc = (t & 7) * 4;
    float4 v = *(const float4*)&W[(size_t)(k0 + kr) * N + n0 + nc];
    T[kr][nc + 0] = f2bf_bits(v.x);
    T[kr][nc + 1] = f2bf_bits(v.y);
    T[kr][nc + 2] = f2bf_bits(v.z);
    T[kr][nc + 3] = f2bf_bits(v.w);
  }
  __syncthreads();
  {
    int nr = t >> 3, kc = (t & 7) * 4;
    ushort4 o;
    o.x = T[kc + 0][nr]; o.y = T[kc + 1][nr];
    o.z = T[kc + 2][nr]; o.w = T[kc + 3][nr];
    *(ushort4*)&WT[(size_t)(n0 + nr) * K + k0 + kc] = o;
  }
}

// ---------------------------------------------------------------------------
// V transpose from fused qkv buffer: qkv[tok][5120 + kvh*128 + d] ->
// VT[(b*8+kvh)*128 + d][1024 s]. 32x32 tiles. grid = (SEQ/32, HD/32, B*NKVH)
// ---------------------------------------------------------------------------
__global__ __launch_bounds__(256)
void vtrans2(const unsigned short* __restrict__ qkv, unsigned short* __restrict__ VT)
{
  __shared__ unsigned short T[32][36];
  const int bh = blockIdx.z;                 // b*8+kvh
  const int s0 = blockIdx.x * 32, d0 = blockIdx.y * 32;
  const int b = bh >> 3, kvh = bh & 7;
  const int t = threadIdx.x;
  {
    int sr = t >> 3, dc = (t & 7) * 4;
    ushort4 v = *(const ushort4*)&qkv[(size_t)(b * SEQ_ + s0 + sr) * QKVW_ + 5120 + kvh * HD_ + d0 + dc];
    T[sr][dc + 0] = v.x; T[sr][dc + 1] = v.y;
    T[sr][dc + 2] = v.z; T[sr][dc + 3] = v.w;
  }
  __syncthreads();
  {
    int dr = t >> 3, sc = (t & 7) * 4;
    ushort4 o;
    o.x = T[sc + 0][dr]; o.y = T[sc + 1][dr];
    o.z = T[sc + 2][dr]; o.w = T[sc + 3][dr];
    *(ushort4*)&VT[((size_t)bh * HD_ + d0 + dr) * SEQ_ + s0 + sc] = o;
  }
}

// ---------------------------------------------------------------------------
// RoPE in place on bf16 pairs inside the fused qkv buffer.
// ---------------------------------------------------------------------------
__global__ __launch_bounds__(256)
void rope2(unsigned int* __restrict__ t, const float* __restrict__ cosf,
           const float* __restrict__ sinf, int shift, int stride_u32, int base_u32)
{
  int idx = blockIdx.x * 256 + threadIdx.x;
  int tok = idx >> shift;
  int rem = idx & ((1 << shift) - 1);
  int d2  = idx & 63;
  int pos = tok & (SEQ_ - 1);
  unsigned int* p = &t[(size_t)tok * stride_u32 + base_u32 + rem];
  unsigned int pv = *p;
  float xe = __uint_as_float(pv << 16);
  float xo = __uint_as_float(pv & 0xFFFF0000u);
  float cv = cosf[pos * 64 + d2];
  float sv = sinf[pos * 64 + d2];
  float oe = xe * cv - xo * sv;
  float oo = xe * sv + xo * cv;
  *p = pack_bf2_rne(oe, oo);
}

// ---------------------------------------------------------------------------
// GEMM v5: 8-phase schedule (m201-template port). C = A @ B^T, bf16 in.
//
// Tile 256x256, K-tile 64; 8 waves (2M x 4N), per-wave 128x64 (acc 8x4).
// LDS [dbuf 2][khalf 2][256][32] per operand = 128 KiB, 1 block/CU.
//
// Per K-tile: 4 phases (kk, mi-half). Each phase:
//   stage 1 half-tile (2 gld16)  | s_waitcnt vmcnt(6)
//   ds_read: 4x A-frag b128 (+4x B-frag at h==0; B reused at h==1)
//   s_barrier ; lgkmcnt(0) ; sched_barrier(0)
//   setprio(1) ; 16 MFMA ; setprio(0) ; s_barrier
//
// Stage order per tile j: [B(j+1)k0, A(j+1)k1, B(j+1)k1, A(j+2)k0] gives
// every half-tile a >=4-phase issue->consume gap, so each wave's vmcnt(6)
// ONE phase before consumption + that phase's end-barrier proves chip-wide
// DMA completion before any wave reads (cross-wave safe). vmcnt never
// drains to 0 in the loop (2 issues/phase, 6 left = last 3 phases).
// WAR: each stage's destination slot's last readers drained >=2 barriers
// earlier (A·k0 slot read at P1/P2, overwritten at P4; B slots at prior tile).
// Tail: clamped dummy stages into dead slots; single vmcnt(0) after loop.
// T2 chunk-XOR swizzle (c ^= (row>>1)&3) as v4 (0 conflicts measured).
// T1 XCD swizzle (grid %8==0 at both call sites).
// ---------------------------------------------------------------------------
template<bool OUT_BF16>
__global__ __launch_bounds__(512, 2)
void gemm_v5(const unsigned short* __restrict__ A,   // [M][K] bf16
             const unsigned short* __restrict__ B,   // [N][K] bf16
             void* __restrict__ Cout, int M, int N, int K)
{
  __shared__ __align__(16) unsigned short As[2][2][256][32];  // 64 KiB
  __shared__ __align__(16) unsigned short Bs[2][2][256][32];  // 64 KiB

  const int tid  = threadIdx.x;
  const int w    = tid >> 6;
  const int lane = tid & 63;
  const int l16  = lane & 15;
  const int quad = lane >> 4;
  const int wr   = w >> 2;        // 0..1  (M)
  const int wc   = w & 3;         // 0..3  (N)

  // T1: XCD-aware swizzle (gridDim.x % 8 == 0 at both call sites)
  int wg = blockIdx.x;
  const int q8 = gridDim.x >> 3;
  wg = (wg & 7) * q8 + (wg >> 3);
  const int nbx = N >> 8;
  const int bm = (wg / nbx) * 256;
  const int bn = (wg % nbx) * 256;

  // staging: half-tile = 256 rows x 32 k = 16 KiB = 2 block-wide gld16.
  // lane -> row w*16 + (lane>>2) (and +128), k-chunk lane&3 (16B each).
  // source chunk pre-swizzled so LDS stays linear (c ^= (row>>1)&3).
  const int srow = w * 16 + (lane >> 2);              // 0..127
  const int scs  = (lane & 3) ^ ((srow >> 1) & 3);    // same for srow+128
  const unsigned short* Ag = &A[(size_t)(bm + srow) * K + scs * 8];
  const unsigned short* Bg = &B[(size_t)(bn + srow) * K + scs * 8];
  const size_t half = (size_t)128 * K;
  char* AsB = (char*)&As[0][0][0][0];
  char* BsB = (char*)&Bs[0][0][0][0];

  auto stageA = [&](int kt, int d, int kk) {
    size_t ko = (size_t)kt * 64 + (size_t)kk * 32;
    char* dst = AsB + (d * 2 + kk) * 16384 + w * 1024;
    gld16(Ag + ko,        dst);
    gld16(Ag + ko + half, dst + 8192);
  };
  auto stageB = [&](int kt, int d, int kk) {
    size_t ko = (size_t)kt * 64 + (size_t)kk * 32;
    char* dst = BsB + (d * 2 + kk) * 16384 + w * 1024;
    gld16(Bg + ko,        dst);
    gld16(Bg + ko + half, dst + 8192);
  };

  floatx4 acc[8][4];
#pragma unroll
  for (int i = 0; i < 8; i++)
#pragma unroll
    for (int j = 0; j < 4; j++) acc[i][j] = (floatx4){0.f, 0.f, 0.f, 0.f};

  // fragment-read swizzle: row = base + 16*i + l16 -> (row>>1)&3 = (l16>>1)&3
  const int cfr = quad ^ ((l16 >> 1) & 3);
  const unsigned short* ArF = &As[0][0][wr * 128 + l16][cfr * 8];
  const unsigned short* BrF = &Bs[0][0][wc * 64  + l16][cfr * 8];

  bf16x8 aF[4], bF[4];
  auto rdA = [&](int d, int kk, int h) {          // 4 x ds_read_b128
    const unsigned short* p = ArF + (d * 2 + kk) * 8192 + h * 2048;
#pragma unroll
    for (int i = 0; i < 4; i++) aF[i] = *(const bf16x8*)&p[i * 512];
  };
  auto rdB = [&](int d, int kk) {                 // 4 x ds_read_b128
    const unsigned short* p = BrF + (d * 2 + kk) * 8192;
#pragma unroll
    for (int j = 0; j < 4; j++) bF[j] = *(const bf16x8*)&p[j * 512];
  };
  auto mfma16 = [&](int h) {
    __builtin_amdgcn_s_setprio(1);
#pragma unroll
    for (int i = 0; i < 4; i++)
#pragma unroll
      for (int j = 0; j < 4; j++)
        acc[h * 4 + i][j] = __builtin_amdgcn_mfma_f32_16x16x32_bf16(aF[i], bF[j], acc[h * 4 + i][j], 0, 0, 0);
    __builtin_amdgcn_s_setprio(0);
  };
  auto vmc6 = [&]() { asm volatile("s_waitcnt vmcnt(6)" ::: "memory"); };
  auto midsync = [&]() {
    __builtin_amdgcn_s_barrier();
    asm volatile("s_waitcnt lgkmcnt(0)" ::: "memory");
    __builtin_amdgcn_sched_barrier(0);
  };
  auto endbar = [&]() { __builtin_amdgcn_s_barrier(); };

  const int nt = K >> 6;   // K-tiles of 64 (= 64 for K=4096; even)

  // ---- prologue: 5 half-tiles (10 loads); confirm tile0 k0+Ak1; barrier.
  stageA(0, 0, 0); stageB(0, 0, 0); stageA(0, 0, 1); stageB(0, 0, 1); stageA(1, 1, 0);
  asm volatile("s_waitcnt vmcnt(4)" ::: "memory");
  __builtin_amdgcn_s_barrier();

#pragma unroll 1
  for (int t = 0; t < nt; t += 2) {
    const int k1 = t + 1;                        // always < nt
    const int k2 = (t + 2 < nt) ? t + 2 : 0;     // clamp -> dummy stage
    const int k3 = (t + 3 < nt) ? t + 3 : 0;

    // ---- tile t (dbuf 0): phases (kk,h) = (0,0)(0,1)(1,0)(1,1)
    stageB(k1, 1, 0); vmc6(); rdA(0, 0, 0); rdB(0, 0); midsync(); mfma16(0); endbar();
    stageA(k1, 1, 1); vmc6(); rdA(0, 0, 1);            midsync(); mfma16(1); endbar();
    stageB(k1, 1, 1); vmc6(); rdA(0, 1, 0); rdB(0, 1); midsync(); mfma16(0); endbar();
    stageA(k2, 0, 0); vmc6(); rdA(0, 1, 1);            midsync(); mfma16(1); endbar();

    // ---- tile t+1 (dbuf 1)
    stageB(k2, 0, 0); vmc6(); rdA(1, 0, 0); rdB(1, 0); midsync(); mfma16(0); endbar();
    stageA(k2, 0, 1); vmc6(); rdA(1, 0, 1);            midsync(); mfma16(1); endbar();
    stageB(k2, 0, 1); vmc6(); rdA(1, 1, 0); rdB(1, 1); midsync(); mfma16(0); endbar();
    stageA(k3, 1, 0); vmc6(); rdA(1, 1, 1);            midsync(); mfma16(1); endbar();
  }

  asm volatile("s_waitcnt vmcnt(0)" ::: "memory");   // drain dummy tail stages

  // ---- epilogue: C write
#pragma unroll
  for (int i = 0; i < 8; i++)
#pragma unroll
    for (int j = 0; j < 4; j++)
#pragma unroll
      for (int r = 0; r < 4; r++) {
        size_t row = bm + wr * 128 + i * 16 + quad * 4 + r;
        size_t col = bn + wc * 64 + j * 16 + l16;
        if (OUT_BF16)
          ((unsigned short*)Cout)[row * N + col] = f2bf_bits(acc[i][j][r]);
        else
          ((float*)Cout)[row * N + col] = acc[i][j][r];
      }
}

// ---------------------------------------------------------------------------
// Flash attention v2 (GQA, causal): S^T = K Q^T via mfma_32x32x16 so softmax
// is per-lane-column; O^T = V^T P^T. All LDS XOR-chunk-swizzled (conflict-free).
// Block = 256 q of one (b,h); 4 waves x 64 q; K-tiles of 64 keys.
// ---------------------------------------------------------------------------
__global__ __launch_bounds__(256, 2)
void flash_attn2(const unsigned short* __restrict__ qkv,
                 const unsigned short* __restrict__ vt,
                 unsigned short* __restrict__ o)
{
  __shared__ __align__(16) unsigned short S_[4][8192];  // 64 KiB total
  unsigned short* Ks = &S_[0][0];            // [64 key][128 d], chunk-swizzled ^ (key&15)
  unsigned short* Vs = &S_[1][0];            // [128 d][64 key], chunk-swizzled ^ (d&7)
  // Ps per wave: S_[2..3], 4096 u16 each:   [64 q][64 key], chunk-swizzled ^ (q&7)

  const int qt = blockIdx.x, h = blockIdx.y, b = blockIdx.z;
  const int kvh = h >> 2;
  const int tid = threadIdx.x, w = tid >> 6, lane = tid & 63;
  const int l31 = lane & 31, hi = lane >> 5;
  const int qb = qt * 256, qw = qb + w * 64;
  unsigned short* Ps = &S_[2][0] + w * 4096;

  const float CEXP = (float)(0.08838834764831845 * 1.4426950408889634); // scale*log2(e)

  // ---- Q fragments in registers (B-operand layout: n=l31, k=hi*8+j per 16-k step)
  bf16x8 qf[2][8];
#pragma unroll
  for (int t2 = 0; t2 < 2; t2++) {
    const unsigned short* qrow =
        &qkv[(size_t)(b * SEQ_ + qw + t2 * 32 + l31) * QKVW_ + h * HD_ + hi * 8];
#pragma unroll
    for (int s = 0; s < 8; s++)
      qf[t2][s] = *(const bf16x8*)&qrow[s * 16];
  }

  floatx16 oa[2][4];   // O^T accumulators: [q-subtile][d-tile], col=q=l31
#pragma unroll
  for (int t2 = 0; t2 < 2; t2++)
#pragma unroll
    for (int dt = 0; dt < 4; dt++)
#pragma unroll
      for (int r = 0; r < 16; r++) oa[t2][dt][r] = 0.f;

  float ms[2] = {-3.0e38f, -3.0e38f};  // running max, SCALED (log2) units
  float ls[2] = {0.f, 0.f};

  const int nk = qb + 256;
  const int qmaxw = qw + 63;

  for (int kb_ = 0; kb_ < nk; kb_ += 64) {
    __syncthreads();   // protect LDS from previous iteration's readers
    // ---- stage K tile: 64 keys x 128 d (16 chunks/row)
    {
      const size_t gbase = (size_t)(b * SEQ_ + kb_) * QKVW_ + 4096 + kvh * HD_;
#pragma unroll
      for (int it = 0; it < 4; it++) {
        int idx = it * 256 + tid;
        int key = idx >> 4, c = idx & 15;
        ushortx8 vld = *(const ushortx8*)&qkv[gbase + (size_t)key * QKVW_ + c * 8];
        *(ushortx8*)&Ks[key * 128 + ((c ^ (key & 15)) * 8)] = vld;
      }
      // ---- stage V^T tile: 128 d x 64 keys (8 chunks/row)
      const size_t vbase = ((size_t)(b * NKVH_ + kvh) * HD_) * SEQ_ + kb_;
#pragma unroll
      for (int it = 0; it < 4; it++) {
        int idx = it * 256 + tid;
        int d = idx >> 3, c = idx & 7;
        ushortx8 vld = *(const ushortx8*)&vt[vbase + (size_t)d * SEQ_ + c * 8];
        *(ushortx8*)&Vs[d * 64 + ((c ^ (d & 7)) * 8)] = vld;
      }
    }
    __syncthreads();

    if (kb_ <= qmaxw) {                      // wave has >=1 unmasked key in tile
      const bool needmask = (kb_ + 63 > qw);

#pragma unroll
      for (int t2 = 0; t2 < 2; t2++) {
        // ---- S^T = K @ Q^T : two 32-key C-tiles, rows=keys, cols=queries
        floatx16 sc[2];
#pragma unroll
        for (int r = 0; r < 16; r++) { sc[0][r] = 0.f; sc[1][r] = 0.f; }
#pragma unroll
        for (int s = 0; s < 8; s++) {
          int c = 2 * s + hi;
          bf16x8 k0 = *(const bf16x8*)&Ks[l31 * 128 + ((c ^ (l31 & 15)) * 8)];
          bf16x8 k1 = *(const bf16x8*)&Ks[(32 + l31) * 128 + ((c ^ ((32 + l31) & 15)) * 8)];
          sc[0] = __builtin_amdgcn_mfma_f32_32x32x16_bf16(k0, qf[t2][s], sc[0], 0, 0, 0);
          sc[1] = __builtin_amdgcn_mfma_f32_32x32x16_bf16(k1, qf[t2][s], sc[1], 0, 0, 0);
        }

        // ---- causal mask (row = key = (r&3)+8*(r>>2)+4*hi; col = q = l31)
        if (needmask) {
          const int q = qw + t2 * 32 + l31;
#pragma unroll
          for (int k2 = 0; k2 < 2; k2++)
#pragma unroll
            for (int r = 0; r < 16; r++) {
              int key = kb_ + k2 * 32 + (r & 3) + 8 * (r >> 2) + 4 * hi;
              if (key > q) sc[k2][r] = -3.0e38f;
            }
        }

        // ---- online softmax for this lane's query (32 vals in-lane + xor32)
        float mx0 = sc[0][0], mx1 = sc[0][1];
#pragma unroll
        for (int r = 2; r < 16; r += 2) { mx0 = fmaxf(mx0, sc[0][r]); mx1 = fmaxf(mx1, sc[0][r + 1]); }
#pragma unroll
        for (int r = 0; r < 16; r += 2) { mx0 = fmaxf(mx0, sc[1][r]); mx1 = fmaxf(mx1, sc[1][r + 1]); }
        float mx = fmaxf(mx0, mx1);
        mx = fmaxf(mx, __shfl_xor(mx, 32));
        float mxs = mx * CEXP;
        float mn = fmaxf(ms[t2], mxs);
        float alpha = fast_exp2(ms[t2] - mn);
        ms[t2] = mn;

        float rs0 = 0.f, rs1 = 0.f;
        const int qloc = t2 * 32 + l31;
#pragma unroll
        for (int k2 = 0; k2 < 2; k2++) {
          unsigned int pk[8];
#pragma unroll
          for (int r = 0; r < 16; r += 2) {
            float p0 = fast_exp2(__builtin_fmaf(sc[k2][r],     CEXP, -mn));
            float p1 = fast_exp2(__builtin_fmaf(sc[k2][r + 1], CEXP, -mn));
            rs0 += p0; rs1 += p1;
            pk[r >> 1] = pack_bf2_trunc(p0, p1);
          }
#pragma unroll
          for (int rq = 0; rq < 4; rq++) {
            int keyoff = k2 * 32 + 8 * rq + 4 * hi;
            int c = keyoff >> 3;
            uint2 val = {pk[rq * 2], pk[rq * 2 + 1]};
            *(uint2*)&Ps[qloc * 64 + ((c ^ (qloc & 7)) * 8) + (keyoff & 7)] = val;
          }
        }
        float rs = rs0 + rs1;
        rs += __shfl_xor(rs, 32);
        ls[t2] = ls[t2] * alpha + rs;

        if (__any(alpha != 1.0f)) {
#pragma unroll
          for (int dt = 0; dt < 4; dt++)
#pragma unroll
            for (int r = 0; r < 16; r++) oa[t2][dt][r] *= alpha;
        }
      }

      // ---- O^T += V^T @ P^T  (A-frag V reused across both q-subtiles)
#pragma unroll
      for (int ks = 0; ks < 4; ks++) {
        int c = 2 * ks + hi;
        bf16x8 pf0, pf1;
        {
          int q0l = l31;
          int q1l = 32 + l31;
          pf0 = *(const bf16x8*)&Ps[q0l * 64 + ((c ^ (q0l & 7)) * 8)];
          pf1 = *(const bf16x8*)&Ps[q1l * 64 + ((c ^ (q1l & 7)) * 8)];
        }
#pragma unroll
        for (int dt = 0; dt < 4; dt++) {
          int d = dt * 32 + l31;
          bf16x8 vf = *(const bf16x8*)&Vs[d * 64 + ((c ^ (d & 7)) * 8)];
          oa[0][dt] = __builtin_amdgcn_mfma_f32_32x32x16_bf16(vf, pf0, oa[0][dt], 0, 0, 0);
          oa[1][dt] = __builtin_amdgcn_mfma_f32_32x32x16_bf16(vf, pf1, oa[1][dt], 0, 0, 0);
        }
      }
    }
  }

  // ---- epilogue: normalize, transpose O^T -> O rows via per-wave LDS patch
  __syncthreads();                 // everyone done reading Ks/Vs/Ps
  unsigned short* patch = &S_[w][0];   // [64 q][128 d], chunk-swizzled ^ (q&7)
  float inv[2] = {1.0f / ls[0], 1.0f / ls[1]};
#pragma unroll
  for (int t2 = 0; t2 < 2; t2++) {
    const int qloc = t2 * 32 + l31;
#pragma unroll
    for (int dt = 0; dt < 4; dt++)
#pragma unroll
      for (int rq = 0; rq < 4; rq++) {
        float a0 = oa[t2][dt][rq * 4 + 0] * inv[t2];
        float a1 = oa[t2][dt][rq * 4 + 1] * inv[t2];
        float a2 = oa[t2][dt][rq * 4 + 2] * inv[t2];
        float a3 = oa[t2][dt][rq * 4 + 3] * inv[t2];
        int doff = dt * 32 + 8 * rq + 4 * hi;
        int c = doff >> 3;
        uint2 val = {pack_bf2_rne(a0, a1), pack_bf2_rne(a2, a3)};
        *(uint2*)&patch[qloc * 128 + ((c ^ (qloc & 7)) * 8) + (doff & 7)] = val;
      }
  }
  // in-wave: write -> read dependency handled by compiler waitcnt
#pragma unroll
  for (int it = 0; it < 16; it++) {
    int idx = it * 64 + lane;
    int row = idx >> 4, c = idx & 15;
    int cc = (c & 7) ^ (row & 7);
    int cs = (c & 8) | cc;          // swizzle only low 3 bits (mask was &7)
    ushortx8 vv = *(const ushortx8*)&patch[row * 128 + cs * 8];
    *(ushortx8*)&o[(size_t)(b * SEQ_ + qb + w * 64 + row) * 4096 + h * HD_ + c * 8] = vv;
  }
}

// ---------------------------------------------------------------------------
extern "C" void kernel_launch(void* const* d_in, const int* in_sizes, int n_in,
                              void* d_out, int out_size, void* d_ws, size_t ws_size,
                              hipStream_t stream)
{
  const float* x  = (const float*)d_in[0];
  const float* wq = (const float*)d_in[1];
  const float* wk = (const float*)d_in[2];
  const float* wv = (const float*)d_in[3];
  const float* wo = (const float*)d_in[4];
  const float* fc = (const float*)d_in[5];
  const float* fs = (const float*)d_in[6];
  float* out = (float*)d_out;

  // bf16 workspace layout (2B elems): total 136 MB
  unsigned short* xb    = (unsigned short*)d_ws;                 // 4096x4096 (32MB), reused as ab
  unsigned short* wqkvT = xb    + (size_t)NTOK_ * DIM_;          // 6144x4096 (48MB), reused as woT
  unsigned short* qkvb  = wqkvT + (size_t)QKVW_ * DIM_;          // 4096x6144 (48MB)
  unsigned short* vtb   = qkvb  + (size_t)NTOK_ * QKVW_;         // 8x128x... (8MB)
  unsigned short* ab    = xb;    // alias: xb dead after QKV proj
  unsigned short* woT   = wqkvT; // alias: wqkvT dead after QKV proj

  dim3 blk(256);

  xconv<<<(NTOK_ * DIM_ / 4) / 256, blk, 0, stream>>>(x, xb);
  wtrans<<<dim3(DIM_ / 32, DIM_ / 32), blk, 0, stream>>>(wq, wqkvT, DIM_, DIM_);
  wtrans<<<dim3((NKVH_ * HD_) / 32, DIM_ / 32), blk, 0, stream>>>(wk, wqkvT + (size_t)4096 * DIM_, DIM_, NKVH_ * HD_);
  wtrans<<<dim3((NKVH_ * HD_) / 32, DIM_ / 32), blk, 0, stream>>>(wv, wqkvT + (size_t)5120 * DIM_, DIM_, NKVH_ * HD_);

  // fused QKV projection: 256x256 tiles, 16x24 = 384 wgs
  gemm_v5<true><<<dim3((NTOK_ / 256) * (QKVW_ / 256)), dim3(512), 0, stream>>>(
      xb, wqkvT, qkvb, NTOK_, QKVW_, DIM_);

  wtrans<<<dim3(DIM_ / 32, DIM_ / 32), blk, 0, stream>>>(wo, woT, DIM_, DIM_);  // aliases wqkvT: after QKV GEMM

  // RoPE on Q (2048 u32/token) and K (512 u32/token at base 2048)
  rope2<<<(NTOK_ * 2048) / 256, blk, 0, stream>>>((unsigned int*)qkvb, fc, fs, 11, 3072, 0);
  rope2<<<(NTOK_ * 512) / 256, blk, 0, stream>>>((unsigned int*)qkvb, fc, fs, 9, 3072, 2048);

  vtrans2<<<dim3(SEQ_ / 32, HD_ / 32, BSZ_ * NKVH_), blk, 0, stream>>>(qkvb, vtb);

  flash_attn2<<<dim3(SEQ_ / 256, NH_, BSZ_), blk, 0, stream>>>(qkvb, vtb, ab);

  // output projection: 256x256 tiles, 16x16 = 256 wgs (perfect packing)
  gemm_v5<false><<<dim3((NTOK_ / 256) * (DIM_ / 256)), dim3(512), 0, stream>>>(
      ab, woT, out, NTOK_, DIM_, DIM_);
}

// Round 5
// 738.582 us; speedup vs baseline: 1.0528x; 1.0528x over previous
//
#include <hip/hip_runtime.h>

#define BSZ_  4
#define SEQ_  1024
#define NH_   32
#define NKVH_ 8
#define HD_   128
#define DIM_  4096
#define NTOK_ (BSZ_ * SEQ_)   // 4096 tokens
#define QKVW_ 6144            // fused QKV output width (u16 elems per token)

typedef float  floatx4  __attribute__((ext_vector_type(4)));
typedef float  floatx16 __attribute__((ext_vector_type(16)));
typedef __bf16 bf16x8   __attribute__((ext_vector_type(8)));
typedef unsigned short ushortx8 __attribute__((ext_vector_type(8)));

__device__ __forceinline__ float fast_exp2(float x) {
  return __builtin_amdgcn_exp2f(x);   // v_exp_f32 (computes 2^x natively)
}

__device__ __forceinline__ unsigned short f2bf_bits(float f) {
  unsigned int u = __float_as_uint(f);
  u += 0x7FFFu + ((u >> 16) & 1u);   // round-to-nearest-even
  return (unsigned short)(u >> 16);
}
__device__ __forceinline__ unsigned int pack_bf2_rne(float lo, float hi_) {
  return (unsigned int)f2bf_bits(lo) | ((unsigned int)f2bf_bits(hi_) << 16);
}
// truncating pack of two fp32 -> bf16x2 (one v_perm_b32)
__device__ __forceinline__ unsigned int pack_bf2_trunc(float lo, float hi_) {
  return __builtin_amdgcn_perm(__float_as_uint(hi_), __float_as_uint(lo), 0x07060302u);
}

// async global->LDS, 16B per lane; LDS dest = wave-uniform base + lane*16
__device__ __forceinline__ void gld16(const void* g, void* l) {
  __builtin_amdgcn_global_load_lds(
      (const __attribute__((address_space(1))) void*)g,
      (__attribute__((address_space(3))) void*)l, 16, 0, 0);
}

// ---------------------------------------------------------------------------
// fp32 -> bf16 convert (contiguous).
// ---------------------------------------------------------------------------
__global__ __launch_bounds__(256)
void xconv(const float* __restrict__ X, unsigned short* __restrict__ XB)
{
  size_t i = ((size_t)blockIdx.x * 256 + threadIdx.x) * 4;
  float4 v = *(const float4*)&X[i];
  ushort4 o;
  o.x = f2bf_bits(v.x); o.y = f2bf_bits(v.y);
  o.z = f2bf_bits(v.z); o.w = f2bf_bits(v.w);
  *(ushort4*)&XB[i] = o;
}

// ---------------------------------------------------------------------------
// Weight transpose-convert: W[K][N] fp32 -> WT[N][K] bf16. 32x32 tiles.
// ---------------------------------------------------------------------------
__global__ __launch_bounds__(256)
void wtrans(const float* __restrict__ W, unsigned short* __restrict__ WT,
            int K, int N)
{
  __shared__ unsigned short T[32][36];
  const int k0 = blockIdx.y * 32, n0 = blockIdx.x * 32;
  const int t = threadIdx.x;
  {
    int kr = t >> 3, nc = (t & 7) * 4;
    float4 v = *(const float4*)&W[(size_t)(k0 + kr) * N + n0 + nc];
    T[kr][nc + 0] = f2bf_bits(v.x);
    T[kr][nc + 1] = f2bf_bits(v.y);
    T[kr][nc + 2] = f2bf_bits(v.z);
    T[kr][nc + 3] = f2bf_bits(v.w);
  }
  __syncthreads();
  {
    int nr = t >> 3, kc = (t & 7) * 4;
    ushort4 o;
    o.x = T[kc + 0][nr]; o.y = T[kc + 1][nr];
    o.z = T[kc + 2][nr]; o.w = T[kc + 3][nr];
    *(ushort4*)&WT[(size_t)(n0 + nr) * K + k0 + kc] = o;
  }
}

// ---------------------------------------------------------------------------
// V transpose from fused qkv buffer: qkv[tok][5120 + kvh*128 + d] ->
// VT[(b*8+kvh)*128 + d][1024 s]. 32x32 tiles. grid = (SEQ/32, HD/32, B*NKVH)
// ---------------------------------------------------------------------------
__global__ __launch_bounds__(256)
void vtrans2(const unsigned short* __restrict__ qkv, unsigned short* __restrict__ VT)
{
  __shared__ unsigned short T[32][36];
  const int bh = blockIdx.z;                 // b*8+kvh
  const int s0 = blockIdx.x * 32, d0 = blockIdx.y * 32;
  const int b = bh >> 3, kvh = bh & 7;
  const int t = threadIdx.x;
  {
    int sr = t >> 3, dc = (t & 7) * 4;
    ushort4 v = *(const ushort4*)&qkv[(size_t)(b * SEQ_ + s0 + sr) * QKVW_ + 5120 + kvh * HD_ + d0 + dc];
    T[sr][dc + 0] = v.x; T[sr][dc + 1] = v.y;
    T[sr][dc + 2] = v.z; T[sr][dc + 3] = v.w;
  }
  __syncthreads();
  {
    int dr = t >> 3, sc = (t & 7) * 4;
    ushort4 o;
    o.x = T[sc + 0][dr]; o.y = T[sc + 1][dr];
    o.z = T[sc + 2][dr]; o.w = T[sc + 3][dr];
    *(ushort4*)&VT[((size_t)bh * HD_ + d0 + dr) * SEQ_ + s0 + sc] = o;
  }
}

// ---------------------------------------------------------------------------
// RoPE in place on bf16 pairs inside the fused qkv buffer.
// ---------------------------------------------------------------------------
__global__ __launch_bounds__(256)
void rope2(unsigned int* __restrict__ t, const float* __restrict__ cosf,
           const float* __restrict__ sinf, int shift, int stride_u32, int base_u32)
{
  int idx = blockIdx.x * 256 + threadIdx.x;
  int tok = idx >> shift;
  int rem = idx & ((1 << shift) - 1);
  int d2  = idx & 63;
  int pos = tok & (SEQ_ - 1);
  unsigned int* p = &t[(size_t)tok * stride_u32 + base_u32 + rem];
  unsigned int pv = *p;
  float xe = __uint_as_float(pv << 16);
  float xo = __uint_as_float(pv & 0xFFFF0000u);
  float cv = cosf[pos * 64 + d2];
  float sv = sinf[pos * 64 + d2];
  float oe = xe * cv - xo * sv;
  float oo = xe * sv + xo * cv;
  *p = pack_bf2_rne(oe, oo);
}

// ---------------------------------------------------------------------------
// Deep-pipelined 256x256 GEMM (round-1 structure, best measured: 237.4 us on
// the QKV shape). C = A @ B^T, bf16 in, bf16/fp32 out.
//  - tile 256x256, BK=32, 8 waves (2M x 4N), per-wave output 128x64
//  - LDS: 4-deep ring per operand, 4 x [256][32] bf16 = 128 KiB total.
//  - 2 phases/tile; each: {ds_read frags | 2 gld16 stage | s_barrier |
//    setprio(1) 16 MFMA setprio(0) | s_barrier}; ONE counted vmcnt(8)/tile.
//  - T2 chunk-XOR swizzle both-sides; T1 XCD swizzle (grid %8==0).
// ---------------------------------------------------------------------------
template<bool OUT_BF16>
__global__ __launch_bounds__(512, 2)
void gemm_bt8(const unsigned short* __restrict__ A,   // [M][K] bf16
              const unsigned short* __restrict__ B,   // [N][K] bf16
              void* __restrict__ Cout, int M, int N, int K)
{
  __shared__ __align__(16) unsigned short As[4][256][32];
  __shared__ __align__(16) unsigned short Bs[4][256][32];

  const int tid  = threadIdx.x;
  const int w    = tid >> 6;
  const int lane = tid & 63;
  const int l16  = lane & 15;
  const int quad = lane >> 4;
  const int wr   = w >> 2;        // 0..1  (M)
  const int wc   = w & 3;         // 0..3  (N)

  // T1: XCD-aware swizzle (requires gridDim.x % 8 == 0 -- true here)
  int wg = blockIdx.x;
  const int q8 = gridDim.x >> 3;
  wg = (wg & 7) * q8 + (wg >> 3);
  const int nbx = N >> 8;
  const int bm = (wg / nbx) * 256;
  const int bn = (wg % nbx) * 256;

  // staging geometry: thread covers row r*128 + srow, 16B chunk cs_stage
  const int srow     = w * 16 + (lane >> 2);              // 0..127
  const int cs_stage = (lane & 3) ^ ((srow >> 1) & 3);    // pre-swizzled src chunk
  const int ntiles   = K >> 5;

  auto stageA = [&](int kt, int buf) {
#pragma unroll
    for (int r = 0; r < 2; r++)
      gld16(&A[(size_t)(bm + r * 128 + srow) * K + (kt << 5) + cs_stage * 8],
            (char*)&As[buf][0][0] + r * 8192 + w * 1024);
  };
  auto stageB = [&](int kt, int buf) {
#pragma unroll
    for (int r = 0; r < 2; r++)
      gld16(&B[(size_t)(bn + r * 128 + srow) * K + (kt << 5) + cs_stage * 8],
            (char*)&Bs[buf][0][0] + r * 8192 + w * 1024);
  };

  floatx4 acc[8][4];
#pragma unroll
  for (int i = 0; i < 8; i++)
#pragma unroll
    for (int j = 0; j < 4; j++) acc[i][j] = (floatx4){0.f, 0.f, 0.f, 0.f};

  // fragment-read swizzle term (row = 16*const + l16 -> s depends on l16 only)
  const int sfrag = (l16 >> 1) & 3;
  const int cfr   = quad ^ sfrag;          // swizzled chunk for frag reads

  // ---- prologue: stage tiles 0,1,2 (12 load-instructions/wave)
#pragma unroll
  for (int t = 0; t < 3; t++) { stageA(t, t); stageB(t, t); }
  asm volatile("s_waitcnt vmcnt(8)" ::: "memory");   // tile 0 landed
  __builtin_amdgcn_s_barrier();

  for (int t = 0; t < ntiles; t++) {
    const int buf  = t & 3;
    const int pbuf = (t + 3) & 3;
    const int pk   = (t + 3 < ntiles) ? (t + 3) : 0;   // clamp: dummy stage keeps vmcnt uniform
    const unsigned short* Ab = &As[buf][0][0];
    const unsigned short* Bb = &Bs[buf][0][0];

    // ---- phase 0: B frags (kept for both phases) + A rows 0..63
    bf16x8 bfr[4], af0[4], af1[4];
#pragma unroll
    for (int nj = 0; nj < 4; nj++)
      bfr[nj] = *(const bf16x8*)&Bb[(wc * 64 + nj * 16 + l16) * 32 + cfr * 8];
#pragma unroll
    for (int i = 0; i < 4; i++)
      af0[i] = *(const bf16x8*)&Ab[(wr * 128 + i * 16 + l16) * 32 + cfr * 8];
    stageA(pk, pbuf);
    __builtin_amdgcn_s_barrier();
    __builtin_amdgcn_s_setprio(1);
#pragma unroll
    for (int i = 0; i < 4; i++)
#pragma unroll
      for (int nj = 0; nj < 4; nj++)
        acc[i][nj] = __builtin_amdgcn_mfma_f32_16x16x32_bf16(af0[i], bfr[nj], acc[i][nj], 0, 0, 0);
    __builtin_amdgcn_s_setprio(0);
    __builtin_amdgcn_s_barrier();

    // ---- phase 1: A rows 64..127 (B frags reused from registers)
#pragma unroll
    for (int i = 0; i < 4; i++)
      af1[i] = *(const bf16x8*)&Ab[(wr * 128 + (4 + i) * 16 + l16) * 32 + cfr * 8];
    stageB(pk, pbuf);
    __builtin_amdgcn_s_barrier();
    __builtin_amdgcn_s_setprio(1);
#pragma unroll
    for (int i = 0; i < 4; i++)
#pragma unroll
      for (int nj = 0; nj < 4; nj++)
        acc[4 + i][nj] = __builtin_amdgcn_mfma_f32_16x16x32_bf16(af1[i], bfr[nj], acc[4 + i][nj], 0, 0, 0);
    __builtin_amdgcn_s_setprio(0);
    // tile t+1 complete after this wait; tiles t+2,t+3 (8 loads) stay in flight
    asm volatile("s_waitcnt vmcnt(8)" ::: "memory");
    __builtin_amdgcn_s_barrier();
  }

  // ---- epilogue: C write (outstanding dummy stages touch only dead LDS)
#pragma unroll
  for (int mi = 0; mi < 8; mi++)
#pragma unroll
    for (int nj = 0; nj < 4; nj++)
#pragma unroll
      for (int r = 0; r < 4; r++) {
        size_t row = bm + wr * 128 + mi * 16 + quad * 4 + r;
        size_t col = bn + wc * 64 + nj * 16 + l16;
        if (OUT_BF16)
          ((unsigned short*)Cout)[row * N + col] = f2bf_bits(acc[mi][nj][r]);
        else
          ((float*)Cout)[row * N + col] = acc[mi][nj][r];
      }
}

// ---------------------------------------------------------------------------
// Flash attention v2 (GQA, causal): S^T = K Q^T via mfma_32x32x16 so softmax
// is per-lane-column; O^T = V^T P^T. All LDS XOR-chunk-swizzled (conflict-free).
// Block = 256 q of one (b,h); 4 waves x 64 q; K-tiles of 64 keys.
//
// Round-5 changes:
//  - 1-D grid (512 blocks) with LPT heavy/light pairing: work per block is
//    (4*qt+4) K-tiles; ordering [qt3 x128 | qt2 x128 | qt0 x128 | qt1 x128]
//    makes breadth-first dispatch co-locate qt3+qt0 (20) and qt2+qt1 (20)
//    on each CU at 2 blocks/CU -> balanced makespan. Perf heuristic only.
//  - T5 setprio(1) around QK^T and PV MFMA clusters (independent co-resident
//    blocks = the regime where setprio measured +4-7%).
// ---------------------------------------------------------------------------
__global__ __launch_bounds__(256, 2)
void flash_attn2(const unsigned short* __restrict__ qkv,
                 const unsigned short* __restrict__ vt,
                 unsigned short* __restrict__ o)
{
  __shared__ __align__(16) unsigned short S_[4][8192];  // 64 KiB total
  unsigned short* Ks = &S_[0][0];            // [64 key][128 d], chunk-swizzled ^ (key&15)
  unsigned short* Vs = &S_[1][0];            // [128 d][64 key], chunk-swizzled ^ (d&7)
  // Ps per wave: S_[2..3], 4096 u16 each:   [64 q][64 key], chunk-swizzled ^ (q&7)

  // ---- LPT remap: grp 0->qt3, 1->qt2, 2->qt0, 3->qt1
  const int bid = blockIdx.x;
  const int grp = bid >> 7;
  const int idx = bid & 127;
  const int qt = (grp == 0) ? 3 : (grp == 1) ? 2 : (grp == 2) ? 0 : 1;
  const int h = idx & 31, b = idx >> 5;

  const int kvh = h >> 2;
  const int tid = threadIdx.x, w = tid >> 6, lane = tid & 63;
  const int l31 = lane & 31, hi = lane >> 5;
  const int qb = qt * 256, qw = qb + w * 64;
  unsigned short* Ps = &S_[2][0] + w * 4096;

  const float CEXP = (float)(0.08838834764831845 * 1.4426950408889634); // scale*log2(e)

  // ---- Q fragments in registers (B-operand layout: n=l31, k=hi*8+j per 16-k step)
  bf16x8 qf[2][8];
#pragma unroll
  for (int t2 = 0; t2 < 2; t2++) {
    const unsigned short* qrow =
        &qkv[(size_t)(b * SEQ_ + qw + t2 * 32 + l31) * QKVW_ + h * HD_ + hi * 8];
#pragma unroll
    for (int s = 0; s < 8; s++)
      qf[t2][s] = *(const bf16x8*)&qrow[s * 16];
  }

  floatx16 oa[2][4];   // O^T accumulators: [q-subtile][d-tile], col=q=l31
#pragma unroll
  for (int t2 = 0; t2 < 2; t2++)
#pragma unroll
    for (int dt = 0; dt < 4; dt++)
#pragma unroll
      for (int r = 0; r < 16; r++) oa[t2][dt][r] = 0.f;

  float ms[2] = {-3.0e38f, -3.0e38f};  // running max, SCALED (log2) units
  float ls[2] = {0.f, 0.f};

  const int nk = qb + 256;
  const int qmaxw = qw + 63;

  for (int kb_ = 0; kb_ < nk; kb_ += 64) {
    __syncthreads();   // protect LDS from previous iteration's readers
    // ---- stage K tile: 64 keys x 128 d (16 chunks/row)
    {
      const size_t gbase = (size_t)(b * SEQ_ + kb_) * QKVW_ + 4096 + kvh * HD_;
#pragma unroll
      for (int it = 0; it < 4; it++) {
        int idx2 = it * 256 + tid;
        int key = idx2 >> 4, c = idx2 & 15;
        ushortx8 vld = *(const ushortx8*)&qkv[gbase + (size_t)key * QKVW_ + c * 8];
        *(ushortx8*)&Ks[key * 128 + ((c ^ (key & 15)) * 8)] = vld;
      }
      // ---- stage V^T tile: 128 d x 64 keys (8 chunks/row)
      const size_t vbase = ((size_t)(b * NKVH_ + kvh) * HD_) * SEQ_ + kb_;
#pragma unroll
      for (int it = 0; it < 4; it++) {
        int idx2 = it * 256 + tid;
        int d = idx2 >> 3, c = idx2 & 7;
        ushortx8 vld = *(const ushortx8*)&vt[vbase + (size_t)d * SEQ_ + c * 8];
        *(ushortx8*)&Vs[d * 64 + ((c ^ (d & 7)) * 8)] = vld;
      }
    }
    __syncthreads();

    if (kb_ <= qmaxw) {                      // wave has >=1 unmasked key in tile
      const bool needmask = (kb_ + 63 > qw);

#pragma unroll
      for (int t2 = 0; t2 < 2; t2++) {
        // ---- S^T = K @ Q^T : two 32-key C-tiles, rows=keys, cols=queries
        floatx16 sc[2];
#pragma unroll
        for (int r = 0; r < 16; r++) { sc[0][r] = 0.f; sc[1][r] = 0.f; }
        __builtin_amdgcn_s_setprio(1);
#pragma unroll
        for (int s = 0; s < 8; s++) {
          int c = 2 * s + hi;
          bf16x8 k0 = *(const bf16x8*)&Ks[l31 * 128 + ((c ^ (l31 & 15)) * 8)];
          bf16x8 k1 = *(const bf16x8*)&Ks[(32 + l31) * 128 + ((c ^ ((32 + l31) & 15)) * 8)];
          sc[0] = __builtin_amdgcn_mfma_f32_32x32x16_bf16(k0, qf[t2][s], sc[0], 0, 0, 0);
          sc[1] = __builtin_amdgcn_mfma_f32_32x32x16_bf16(k1, qf[t2][s], sc[1], 0, 0, 0);
        }
        __builtin_amdgcn_s_setprio(0);

        // ---- causal mask (row = key = (r&3)+8*(r>>2)+4*hi; col = q = l31)
        if (needmask) {
          const int q = qw + t2 * 32 + l31;
#pragma unroll
          for (int k2 = 0; k2 < 2; k2++)
#pragma unroll
            for (int r = 0; r < 16; r++) {
              int key = kb_ + k2 * 32 + (r & 3) + 8 * (r >> 2) + 4 * hi;
              if (key > q) sc[k2][r] = -3.0e38f;
            }
        }

        // ---- online softmax for this lane's query (32 vals in-lane + xor32)
        float mx0 = sc[0][0], mx1 = sc[0][1];
#pragma unroll
        for (int r = 2; r < 16; r += 2) { mx0 = fmaxf(mx0, sc[0][r]); mx1 = fmaxf(mx1, sc[0][r + 1]); }
#pragma unroll
        for (int r = 0; r < 16; r += 2) { mx0 = fmaxf(mx0, sc[1][r]); mx1 = fmaxf(mx1, sc[1][r + 1]); }
        float mx = fmaxf(mx0, mx1);
        mx = fmaxf(mx, __shfl_xor(mx, 32));
        float mxs = mx * CEXP;
        float mn = fmaxf(ms[t2], mxs);
        float alpha = fast_exp2(ms[t2] - mn);
        ms[t2] = mn;

        float rs0 = 0.f, rs1 = 0.f;
        const int qloc = t2 * 32 + l31;
#pragma unroll
        for (int k2 = 0; k2 < 2; k2++) {
          unsigned int pk[8];
#pragma unroll
          for (int r = 0; r < 16; r += 2) {
            float p0 = fast_exp2(__builtin_fmaf(sc[k2][r],     CEXP, -mn));
            float p1 = fast_exp2(__builtin_fmaf(sc[k2][r + 1], CEXP, -mn));
            rs0 += p0; rs1 += p1;
            pk[r >> 1] = pack_bf2_trunc(p0, p1);
          }
#pragma unroll
          for (int rq = 0; rq < 4; rq++) {
            int keyoff = k2 * 32 + 8 * rq + 4 * hi;
            int c = keyoff >> 3;
            uint2 val = {pk[rq * 2], pk[rq * 2 + 1]};
            *(uint2*)&Ps[qloc * 64 + ((c ^ (qloc & 7)) * 8) + (keyoff & 7)] = val;
          }
        }
        float rs = rs0 + rs1;
        rs += __shfl_xor(rs, 32);
        ls[t2] = ls[t2] * alpha + rs;

        if (__any(alpha != 1.0f)) {
#pragma unroll
          for (int dt = 0; dt < 4; dt++)
#pragma unroll
            for (int r = 0; r < 16; r++) oa[t2][dt][r] *= alpha;
        }
      }

      // ---- O^T += V^T @ P^T  (A-frag V reused across both q-subtiles)
      __builtin_amdgcn_s_setprio(1);
#pragma unroll
      for (int ks = 0; ks < 4; ks++) {
        int c = 2 * ks + hi;
        bf16x8 pf0, pf1;
        {
          int q0l = l31;
          int q1l = 32 + l31;
          pf0 = *(const bf16x8*)&Ps[q0l * 64 + ((c ^ (q0l & 7)) * 8)];
          pf1 = *(const bf16x8*)&Ps[q1l * 64 + ((c ^ (q1l & 7)) * 8)];
        }
#pragma unroll
        for (int dt = 0; dt < 4; dt++) {
          int d = dt * 32 + l31;
          bf16x8 vf = *(const bf16x8*)&Vs[d * 64 + ((c ^ (d & 7)) * 8)];
          oa[0][dt] = __builtin_amdgcn_mfma_f32_32x32x16_bf16(vf, pf0, oa[0][dt], 0, 0, 0);
          oa[1][dt] = __builtin_amdgcn_mfma_f32_32x32x16_bf16(vf, pf1, oa[1][dt], 0, 0, 0);
        }
      }
      __builtin_amdgcn_s_setprio(0);
    }
  }

  // ---- epilogue: normalize, transpose O^T -> O rows via per-wave LDS patch
  __syncthreads();                 // everyone done reading Ks/Vs/Ps
  unsigned short* patch = &S_[w][0];   // [64 q][128 d], chunk-swizzled ^ (q&7)
  float inv[2] = {1.0f / ls[0], 1.0f / ls[1]};
#pragma unroll
  for (int t2 = 0; t2 < 2; t2++) {
    const int qloc = t2 * 32 + l31;
#pragma unroll
    for (int dt = 0; dt < 4; dt++)
#pragma unroll
      for (int rq = 0; rq < 4; rq++) {
        float a0 = oa[t2][dt][rq * 4 + 0] * inv[t2];
        float a1 = oa[t2][dt][rq * 4 + 1] * inv[t2];
        float a2 = oa[t2][dt][rq * 4 + 2] * inv[t2];
        float a3 = oa[t2][dt][rq * 4 + 3] * inv[t2];
        int doff = dt * 32 + 8 * rq + 4 * hi;
        int c = doff >> 3;
        uint2 val = {pack_bf2_rne(a0, a1), pack_bf2_rne(a2, a3)};
        *(uint2*)&patch[qloc * 128 + ((c ^ (qloc & 7)) * 8) + (doff & 7)] = val;
      }
  }
  // in-wave: write -> read dependency handled by compiler waitcnt
#pragma unroll
  for (int it = 0; it < 16; it++) {
    int idx2 = it * 64 + lane;
    int row = idx2 >> 4, c = idx2 & 15;
    int cc = (c & 7) ^ (row & 7);
    int cs = (c & 8) | cc;          // swizzle only low 3 bits (mask was &7)
    ushortx8 vv = *(const ushortx8*)&patch[row * 128 + cs * 8];
    *(ushortx8*)&o[(size_t)(b * SEQ_ + qb + w * 64 + row) * 4096 + h * HD_ + c * 8] = vv;
  }
}

// ---------------------------------------------------------------------------
extern "C" void kernel_launch(void* const* d_in, const int* in_sizes, int n_in,
                              void* d_out, int out_size, void* d_ws, size_t ws_size,
                              hipStream_t stream)
{
  const float* x  = (const float*)d_in[0];
  const float* wq = (const float*)d_in[1];
  const float* wk = (const float*)d_in[2];
  const float* wv = (const float*)d_in[3];
  const float* wo = (const float*)d_in[4];
  const float* fc = (const float*)d_in[5];
  const float* fs = (const float*)d_in[6];
  float* out = (float*)d_out;

  // bf16 workspace layout (2B elems): total 136 MB
  unsigned short* xb    = (unsigned short*)d_ws;                 // 4096x4096 (32MB), reused as ab
  unsigned short* wqkvT = xb    + (size_t)NTOK_ * DIM_;          // 6144x4096 (48MB), reused as woT
  unsigned short* qkvb  = wqkvT + (size_t)QKVW_ * DIM_;          // 4096x6144 (48MB)
  unsigned short* vtb   = qkvb  + (size_t)NTOK_ * QKVW_;         // 8x128x... (8MB)
  unsigned short* ab    = xb;    // alias: xb dead after QKV proj
  unsigned short* woT   = wqkvT; // alias: wqkvT dead after QKV proj

  dim3 blk(256);

  xconv<<<(NTOK_ * DIM_ / 4) / 256, blk, 0, stream>>>(x, xb);
  wtrans<<<dim3(DIM_ / 32, DIM_ / 32), blk, 0, stream>>>(wq, wqkvT, DIM_, DIM_);
  wtrans<<<dim3((NKVH_ * HD_) / 32, DIM_ / 32), blk, 0, stream>>>(wk, wqkvT + (size_t)4096 * DIM_, DIM_, NKVH_ * HD_);
  wtrans<<<dim3((NKVH_ * HD_) / 32, DIM_ / 32), blk, 0, stream>>>(wv, wqkvT + (size_t)5120 * DIM_, DIM_, NKVH_ * HD_);

  // fused QKV projection: [4096 tok][6144] bf16 -- 256x256 tiles, 24x16 = 384 wgs
  gemm_bt8<true><<<dim3((QKVW_ / 256) * (NTOK_ / 256)), dim3(512), 0, stream>>>(
      xb, wqkvT, qkvb, NTOK_, QKVW_, DIM_);

  wtrans<<<dim3(DIM_ / 32, DIM_ / 32), blk, 0, stream>>>(wo, woT, DIM_, DIM_);  // aliases wqkvT: after QKV GEMM

  // RoPE on Q (2048 u32/token) and K (512 u32/token at base 2048)
  rope2<<<(NTOK_ * 2048) / 256, blk, 0, stream>>>((unsigned int*)qkvb, fc, fs, 11, 3072, 0);
  rope2<<<(NTOK_ * 512) / 256, blk, 0, stream>>>((unsigned int*)qkvb, fc, fs, 9, 3072, 2048);

  vtrans2<<<dim3(SEQ_ / 32, HD_ / 32, BSZ_ * NKVH_), blk, 0, stream>>>(qkvb, vtb);

  // flash attention: 1-D LPT-ordered grid (512 blocks)
  flash_attn2<<<dim3((SEQ_ / 256) * NH_ * BSZ_), blk, 0, stream>>>(qkvb, vtb, ab);

  // output projection: 16x16 = 256 wgs (perfectly balanced on 256 CUs)
  gemm_bt8<false><<<dim3((DIM_ / 256) * (NTOK_ / 256)), dim3(512), 0, stream>>>(
      ab, woT, out, NTOK_, DIM_, DIM_);
}

// Round 6
// 717.340 us; speedup vs baseline: 1.0839x; 1.0296x over previous
//
#include <hip/hip_runtime.h>

#define BSZ_  4
#define SEQ_  1024
#define NH_   32
#define NKVH_ 8
#define HD_   128
#define DIM_  4096
#define NTOK_ (BSZ_ * SEQ_)   // 4096 tokens
#define QKVW_ 6144            // fused QKV output width (u16 elems per token)

typedef float  floatx4  __attribute__((ext_vector_type(4)));
typedef float  floatx16 __attribute__((ext_vector_type(16)));
typedef __bf16 bf16x8   __attribute__((ext_vector_type(8)));
typedef unsigned short ushortx8 __attribute__((ext_vector_type(8)));

__device__ __forceinline__ float fast_exp2(float x) {
  return __builtin_amdgcn_exp2f(x);   // v_exp_f32 (computes 2^x natively)
}

__device__ __forceinline__ unsigned short f2bf_bits(float f) {
  unsigned int u = __float_as_uint(f);
  u += 0x7FFFu + ((u >> 16) & 1u);   // round-to-nearest-even
  return (unsigned short)(u >> 16);
}
__device__ __forceinline__ unsigned int pack_bf2_rne(float lo, float hi_) {
  return (unsigned int)f2bf_bits(lo) | ((unsigned int)f2bf_bits(hi_) << 16);
}
// truncating pack of two fp32 -> bf16x2 (one v_perm_b32)
__device__ __forceinline__ unsigned int pack_bf2_trunc(float lo, float hi_) {
  return __builtin_amdgcn_perm(__float_as_uint(hi_), __float_as_uint(lo), 0x07060302u);
}

// async global->LDS, 16B per lane; LDS dest = wave-uniform base + lane*16
__device__ __forceinline__ void gld16(const void* g, void* l) {
  __builtin_amdgcn_global_load_lds(
      (const __attribute__((address_space(1))) void*)g,
      (__attribute__((address_space(3))) void*)l, 16, 0, 0);
}

// ---------------------------------------------------------------------------
// fp32 -> bf16 convert (contiguous).
// ---------------------------------------------------------------------------
__global__ __launch_bounds__(256)
void xconv(const float* __restrict__ X, unsigned short* __restrict__ XB)
{
  size_t i = ((size_t)blockIdx.x * 256 + threadIdx.x) * 4;
  float4 v = *(const float4*)&X[i];
  ushort4 o;
  o.x = f2bf_bits(v.x); o.y = f2bf_bits(v.y);
  o.z = f2bf_bits(v.z); o.w = f2bf_bits(v.w);
  *(ushort4*)&XB[i] = o;
}

// ---------------------------------------------------------------------------
// Weight transpose-convert: W[K][N] fp32 -> WT[N][K] bf16. 32x32 tiles.
// ---------------------------------------------------------------------------
__global__ __launch_bounds__(256)
void wtrans(const float* __restrict__ W, unsigned short* __restrict__ WT,
            int K, int N)
{
  __shared__ unsigned short T[32][36];
  const int k0 = blockIdx.y * 32, n0 = blockIdx.x * 32;
  const int t = threadIdx.x;
  {
    int kr = t >> 3, nc = (t & 7) * 4;
    float4 v = *(const float4*)&W[(size_t)(k0 + kr) * N + n0 + nc];
    T[kr][nc + 0] = f2bf_bits(v.x);
    T[kr][nc + 1] = f2bf_bits(v.y);
    T[kr][nc + 2] = f2bf_bits(v.z);
    T[kr][nc + 3] = f2bf_bits(v.w);
  }
  __syncthreads();
  {
    int nr = t >> 3, kc = (t & 7) * 4;
    ushort4 o;
    o.x = T[kc + 0][nr]; o.y = T[kc + 1][nr];
    o.z = T[kc + 2][nr]; o.w = T[kc + 3][nr];
    *(ushort4*)&WT[(size_t)(n0 + nr) * K + k0 + kc] = o;
  }
}

// ---------------------------------------------------------------------------
// V transpose from fused qkv buffer: qkv[tok][5120 + kvh*128 + d] ->
// VT[(b*8+kvh)*128 + d][1024 s]. 32x32 tiles. grid = (SEQ/32, HD/32, B*NKVH)
// ---------------------------------------------------------------------------
__global__ __launch_bounds__(256)
void vtrans2(const unsigned short* __restrict__ qkv, unsigned short* __restrict__ VT)
{
  __shared__ unsigned short T[32][36];
  const int bh = blockIdx.z;                 // b*8+kvh
  const int s0 = blockIdx.x * 32, d0 = blockIdx.y * 32;
  const int b = bh >> 3, kvh = bh & 7;
  const int t = threadIdx.x;
  {
    int sr = t >> 3, dc = (t & 7) * 4;
    ushort4 v = *(const ushort4*)&qkv[(size_t)(b * SEQ_ + s0 + sr) * QKVW_ + 5120 + kvh * HD_ + d0 + dc];
    T[sr][dc + 0] = v.x; T[sr][dc + 1] = v.y;
    T[sr][dc + 2] = v.z; T[sr][dc + 3] = v.w;
  }
  __syncthreads();
  {
    int dr = t >> 3, sc = (t & 7) * 4;
    ushort4 o;
    o.x = T[sc + 0][dr]; o.y = T[sc + 1][dr];
    o.z = T[sc + 2][dr]; o.w = T[sc + 3][dr];
    *(ushort4*)&VT[((size_t)bh * HD_ + d0 + dr) * SEQ_ + s0 + sc] = o;
  }
}

// ---------------------------------------------------------------------------
// RoPE in place on bf16 pairs inside the fused qkv buffer.
// ---------------------------------------------------------------------------
__global__ __launch_bounds__(256)
void rope2(unsigned int* __restrict__ t, const float* __restrict__ cosf,
           const float* __restrict__ sinf, int shift, int stride_u32, int base_u32)
{
  int idx = blockIdx.x * 256 + threadIdx.x;
  int tok = idx >> shift;
  int rem = idx & ((1 << shift) - 1);
  int d2  = idx & 63;
  int pos = tok & (SEQ_ - 1);
  unsigned int* p = &t[(size_t)tok * stride_u32 + base_u32 + rem];
  unsigned int pv = *p;
  float xe = __uint_as_float(pv << 16);
  float xo = __uint_as_float(pv & 0xFFFF0000u);
  float cv = cosf[pos * 64 + d2];
  float sv = sinf[pos * 64 + d2];
  float oe = xe * cv - xo * sv;
  float oo = xe * sv + xo * cv;
  *p = pack_bf2_rne(oe, oo);
}

// ---------------------------------------------------------------------------
// Deep-pipelined 256x256 GEMM (round-1 structure, best measured). C = A @ B^T.
//  - tile 256x256, BK=32, 8 waves (2M x 4N), per-wave output 128x64
//  - LDS: 4-deep ring per operand, 4 x [256][32] bf16 = 128 KiB total.
//  - 2 phases/tile; each: {ds_read frags | 2 gld16 stage | s_barrier |
//    setprio(1) 16 MFMA setprio(0) | s_barrier}; ONE counted vmcnt(8)/tile.
//  - T2 chunk-XOR swizzle both-sides; T1 XCD swizzle (grid %8==0).
// ---------------------------------------------------------------------------
template<bool OUT_BF16>
__global__ __launch_bounds__(512, 2)
void gemm_bt8(const unsigned short* __restrict__ A,   // [M][K] bf16
              const unsigned short* __restrict__ B,   // [N][K] bf16
              void* __restrict__ Cout, int M, int N, int K)
{
  __shared__ __align__(16) unsigned short As[4][256][32];
  __shared__ __align__(16) unsigned short Bs[4][256][32];

  const int tid  = threadIdx.x;
  const int w    = tid >> 6;
  const int lane = tid & 63;
  const int l16  = lane & 15;
  const int quad = lane >> 4;
  const int wr   = w >> 2;        // 0..1  (M)
  const int wc   = w & 3;         // 0..3  (N)

  // T1: XCD-aware swizzle (requires gridDim.x % 8 == 0 -- true here)
  int wg = blockIdx.x;
  const int q8 = gridDim.x >> 3;
  wg = (wg & 7) * q8 + (wg >> 3);
  const int nbx = N >> 8;
  const int bm = (wg / nbx) * 256;
  const int bn = (wg % nbx) * 256;

  // staging geometry: thread covers row r*128 + srow, 16B chunk cs_stage
  const int srow     = w * 16 + (lane >> 2);              // 0..127
  const int cs_stage = (lane & 3) ^ ((srow >> 1) & 3);    // pre-swizzled src chunk
  const int ntiles   = K >> 5;

  auto stageA = [&](int kt, int buf) {
#pragma unroll
    for (int r = 0; r < 2; r++)
      gld16(&A[(size_t)(bm + r * 128 + srow) * K + (kt << 5) + cs_stage * 8],
            (char*)&As[buf][0][0] + r * 8192 + w * 1024);
  };
  auto stageB = [&](int kt, int buf) {
#pragma unroll
    for (int r = 0; r < 2; r++)
      gld16(&B[(size_t)(bn + r * 128 + srow) * K + (kt << 5) + cs_stage * 8],
            (char*)&Bs[buf][0][0] + r * 8192 + w * 1024);
  };

  floatx4 acc[8][4];
#pragma unroll
  for (int i = 0; i < 8; i++)
#pragma unroll
    for (int j = 0; j < 4; j++) acc[i][j] = (floatx4){0.f, 0.f, 0.f, 0.f};

  // fragment-read swizzle term (row = 16*const + l16 -> s depends on l16 only)
  const int sfrag = (l16 >> 1) & 3;
  const int cfr   = quad ^ sfrag;          // swizzled chunk for frag reads

  // ---- prologue: stage tiles 0,1,2 (12 load-instructions/wave)
#pragma unroll
  for (int t = 0; t < 3; t++) { stageA(t, t); stageB(t, t); }
  asm volatile("s_waitcnt vmcnt(8)" ::: "memory");   // tile 0 landed
  __builtin_amdgcn_s_barrier();

  for (int t = 0; t < ntiles; t++) {
    const int buf  = t & 3;
    const int pbuf = (t + 3) & 3;
    const int pk   = (t + 3 < ntiles) ? (t + 3) : 0;   // clamp: dummy stage keeps vmcnt uniform
    const unsigned short* Ab = &As[buf][0][0];
    const unsigned short* Bb = &Bs[buf][0][0];

    // ---- phase 0: B frags (kept for both phases) + A rows 0..63
    bf16x8 bfr[4], af0[4], af1[4];
#pragma unroll
    for (int nj = 0; nj < 4; nj++)
      bfr[nj] = *(const bf16x8*)&Bb[(wc * 64 + nj * 16 + l16) * 32 + cfr * 8];
#pragma unroll
    for (int i = 0; i < 4; i++)
      af0[i] = *(const bf16x8*)&Ab[(wr * 128 + i * 16 + l16) * 32 + cfr * 8];
    stageA(pk, pbuf);
    __builtin_amdgcn_s_barrier();
    __builtin_amdgcn_s_setprio(1);
#pragma unroll
    for (int i = 0; i < 4; i++)
#pragma unroll
      for (int nj = 0; nj < 4; nj++)
        acc[i][nj] = __builtin_amdgcn_mfma_f32_16x16x32_bf16(af0[i], bfr[nj], acc[i][nj], 0, 0, 0);
    __builtin_amdgcn_s_setprio(0);
    __builtin_amdgcn_s_barrier();

    // ---- phase 1: A rows 64..127 (B frags reused from registers)
#pragma unroll
    for (int i = 0; i < 4; i++)
      af1[i] = *(const bf16x8*)&Ab[(wr * 128 + (4 + i) * 16 + l16) * 32 + cfr * 8];
    stageB(pk, pbuf);
    __builtin_amdgcn_s_barrier();
    __builtin_amdgcn_s_setprio(1);
#pragma unroll
    for (int i = 0; i < 4; i++)
#pragma unroll
      for (int nj = 0; nj < 4; nj++)
        acc[4 + i][nj] = __builtin_amdgcn_mfma_f32_16x16x32_bf16(af1[i], bfr[nj], acc[4 + i][nj], 0, 0, 0);
    __builtin_amdgcn_s_setprio(0);
    // tile t+1 complete after this wait; tiles t+2,t+3 (8 loads) stay in flight
    asm volatile("s_waitcnt vmcnt(8)" ::: "memory");
    __builtin_amdgcn_s_barrier();
  }

  // ---- epilogue: C write (outstanding dummy stages touch only dead LDS)
#pragma unroll
  for (int mi = 0; mi < 8; mi++)
#pragma unroll
    for (int nj = 0; nj < 4; nj++)
#pragma unroll
      for (int r = 0; r < 4; r++) {
        size_t row = bm + wr * 128 + mi * 16 + quad * 4 + r;
        size_t col = bn + wc * 64 + nj * 16 + l16;
        if (OUT_BF16)
          ((unsigned short*)Cout)[row * N + col] = f2bf_bits(acc[mi][nj][r]);
        else
          ((float*)Cout)[row * N + col] = acc[mi][nj][r];
      }
}

// ---------------------------------------------------------------------------
// Flash attention v2 (GQA, causal): S^T = K Q^T via mfma_32x32x16 so softmax
// is per-lane-column; O^T = V^T P^T. All LDS XOR-chunk-swizzled (conflict-free).
// Block = 256 q of one (b,h); 4 waves x 64 q; K-tiles of 64 keys.
//
// Round-6 changes:
//  - T14 async-STAGE: issue tile t+1's K/V global loads into REGISTERS before
//    compute of tile t; write regs->LDS after the next WAR barrier. The
//    post-write barrier is a raw s_barrier preceded by lgkmcnt(0) ONLY
//    (ds_writes visible; prefetch loads stay in flight across the barrier --
//    __syncthreads would drain vmcnt and kill the pipeline). The reg-consume
//    at the write site gives the prefetch a full compute phase of latency
//    cover.
//  - T13 defer-max (THR=8 log2-units): skip max-update/rescale unless the
//    tile max grows by >8; P bounded by 2^8, safe in bf16/fp32 accum.
//  - (kept from R5) LPT heavy/light grid pairing + setprio on MFMA clusters.
// ---------------------------------------------------------------------------
__global__ __launch_bounds__(256, 2)
void flash_attn2(const unsigned short* __restrict__ qkv,
                 const unsigned short* __restrict__ vt,
                 unsigned short* __restrict__ o)
{
  __shared__ __align__(16) unsigned short S_[4][8192];  // 64 KiB total
  unsigned short* Ks = &S_[0][0];            // [64 key][128 d], chunk-swizzled ^ (key&15)
  unsigned short* Vs = &S_[1][0];            // [128 d][64 key], chunk-swizzled ^ (d&7)
  // Ps per wave: S_[2..3], 4096 u16 each:   [64 q][64 key], chunk-swizzled ^ (q&7)

  // ---- LPT remap: grp 0->qt3, 1->qt2, 2->qt0, 3->qt1
  const int bid = blockIdx.x;
  const int grp = bid >> 7;
  const int idx = bid & 127;
  const int qt = (grp == 0) ? 3 : (grp == 1) ? 2 : (grp == 2) ? 0 : 1;
  const int h = idx & 31, b = idx >> 5;

  const int kvh = h >> 2;
  const int tid = threadIdx.x, w = tid >> 6, lane = tid & 63;
  const int l31 = lane & 31, hi = lane >> 5;
  const int qb = qt * 256, qw = qb + w * 64;
  unsigned short* Ps = &S_[2][0] + w * 4096;

  const float CEXP = (float)(0.08838834764831845 * 1.4426950408889634); // scale*log2(e)

  // ---- Q fragments in registers (B-operand layout: n=l31, k=hi*8+j per 16-k step)
  bf16x8 qf[2][8];
#pragma unroll
  for (int t2 = 0; t2 < 2; t2++) {
    const unsigned short* qrow =
        &qkv[(size_t)(b * SEQ_ + qw + t2 * 32 + l31) * QKVW_ + h * HD_ + hi * 8];
#pragma unroll
    for (int s = 0; s < 8; s++)
      qf[t2][s] = *(const bf16x8*)&qrow[s * 16];
  }

  floatx16 oa[2][4];   // O^T accumulators: [q-subtile][d-tile], col=q=l31
#pragma unroll
  for (int t2 = 0; t2 < 2; t2++)
#pragma unroll
    for (int dt = 0; dt < 4; dt++)
#pragma unroll
      for (int r = 0; r < 16; r++) oa[t2][dt][r] = 0.f;

  float ms[2] = {-3.0e38f, -3.0e38f};  // running max, SCALED (log2) units
  float ls[2] = {0.f, 0.f};

  const int nk = qb + 256;
  const int qmaxw = qw + 63;

  // ---- T14 staging state: next tile's K/V in registers (32 VGPR)
  ushortx8 kreg[4], vreg[4];
  const size_t kg0 = (size_t)(b * SEQ_) * QKVW_ + 4096 + kvh * HD_;
  const size_t vg0 = ((size_t)(b * NKVH_ + kvh) * HD_) * SEQ_;
  const int krow = tid >> 4, kc = tid & 15;        // K: covers 16 keys/iter
  const int vrow = tid >> 3, vc = tid & 7;         // V: covers 32 d/iter

  auto issue_loads = [&](int kb) {
    const size_t gb = kg0 + (size_t)kb * QKVW_;
#pragma unroll
    for (int it = 0; it < 4; it++)
      kreg[it] = *(const ushortx8*)&qkv[gb + (size_t)(it * 16 + krow) * QKVW_ + kc * 8];
    const size_t vb = vg0 + kb;
#pragma unroll
    for (int it = 0; it < 4; it++)
      vreg[it] = *(const ushortx8*)&vt[vb + (size_t)(it * 32 + vrow) * SEQ_ + vc * 8];
  };
  auto write_lds = [&]() {
#pragma unroll
    for (int it = 0; it < 4; it++) {
      int key = it * 16 + krow;
      *(ushortx8*)&Ks[key * 128 + ((kc ^ (key & 15)) * 8)] = kreg[it];
    }
#pragma unroll
    for (int it = 0; it < 4; it++) {
      int d = it * 32 + vrow;
      *(ushortx8*)&Vs[d * 64 + ((vc ^ (d & 7)) * 8)] = vreg[it];
    }
  };

  issue_loads(0);

  for (int kb_ = 0; kb_ < nk; kb_ += 64) {
    __syncthreads();   // WAR: all readers of previous tile done (drains vmcnt
                       // for the prefetch we are about to consume -- desired)
    write_lds();
    if (kb_ + 64 < nk) issue_loads(kb_ + 64);   // prefetch under compute
    asm volatile("s_waitcnt lgkmcnt(0)" ::: "memory");   // ds_writes visible
    __builtin_amdgcn_s_barrier();                        // loads stay in flight

    if (kb_ <= qmaxw) {                      // wave has >=1 unmasked key in tile
      const bool needmask = (kb_ + 63 > qw);

#pragma unroll
      for (int t2 = 0; t2 < 2; t2++) {
        // ---- S^T = K @ Q^T : two 32-key C-tiles, rows=keys, cols=queries
        floatx16 sc[2];
#pragma unroll
        for (int r = 0; r < 16; r++) { sc[0][r] = 0.f; sc[1][r] = 0.f; }
        __builtin_amdgcn_s_setprio(1);
#pragma unroll
        for (int s = 0; s < 8; s++) {
          int c = 2 * s + hi;
          bf16x8 k0 = *(const bf16x8*)&Ks[l31 * 128 + ((c ^ (l31 & 15)) * 8)];
          bf16x8 k1 = *(const bf16x8*)&Ks[(32 + l31) * 128 + ((c ^ ((32 + l31) & 15)) * 8)];
          sc[0] = __builtin_amdgcn_mfma_f32_32x32x16_bf16(k0, qf[t2][s], sc[0], 0, 0, 0);
          sc[1] = __builtin_amdgcn_mfma_f32_32x32x16_bf16(k1, qf[t2][s], sc[1], 0, 0, 0);
        }
        __builtin_amdgcn_s_setprio(0);

        // ---- causal mask (row = key = (r&3)+8*(r>>2)+4*hi; col = q = l31)
        if (needmask) {
          const int q = qw + t2 * 32 + l31;
#pragma unroll
          for (int k2 = 0; k2 < 2; k2++)
#pragma unroll
            for (int r = 0; r < 16; r++) {
              int key = kb_ + k2 * 32 + (r & 3) + 8 * (r >> 2) + 4 * hi;
              if (key > q) sc[k2][r] = -3.0e38f;
            }
        }

        // ---- online softmax for this lane's query (32 vals in-lane + xor32)
        float mx0 = sc[0][0], mx1 = sc[0][1];
#pragma unroll
        for (int r = 2; r < 16; r += 2) { mx0 = fmaxf(mx0, sc[0][r]); mx1 = fmaxf(mx1, sc[0][r + 1]); }
#pragma unroll
        for (int r = 0; r < 16; r += 2) { mx0 = fmaxf(mx0, sc[1][r]); mx1 = fmaxf(mx1, sc[1][r + 1]); }
        float mx = fmaxf(mx0, mx1);
        mx = fmaxf(mx, __shfl_xor(mx, 32));
        float mxs = mx * CEXP;

        // ---- T13 defer-max: keep old max unless growth > 8 (P <= 2^8)
        float mn, alpha;
        if (__all(mxs - ms[t2] <= 8.0f)) {
          mn = ms[t2]; alpha = 1.0f;
        } else {
          mn = fmaxf(ms[t2], mxs);
          alpha = fast_exp2(ms[t2] - mn);
          ms[t2] = mn;
        }

        float rs0 = 0.f, rs1 = 0.f;
        const int qloc = t2 * 32 + l31;
#pragma unroll
        for (int k2 = 0; k2 < 2; k2++) {
          unsigned int pk[8];
#pragma unroll
          for (int r = 0; r < 16; r += 2) {
            float p0 = fast_exp2(__builtin_fmaf(sc[k2][r],     CEXP, -mn));
            float p1 = fast_exp2(__builtin_fmaf(sc[k2][r + 1], CEXP, -mn));
            rs0 += p0; rs1 += p1;
            pk[r >> 1] = pack_bf2_trunc(p0, p1);
          }
#pragma unroll
          for (int rq = 0; rq < 4; rq++) {
            int keyoff = k2 * 32 + 8 * rq + 4 * hi;
            int c = keyoff >> 3;
            uint2 val = {pk[rq * 2], pk[rq * 2 + 1]};
            *(uint2*)&Ps[qloc * 64 + ((c ^ (qloc & 7)) * 8) + (keyoff & 7)] = val;
          }
        }
        float rs = rs0 + rs1;
        rs += __shfl_xor(rs, 32);
        ls[t2] = ls[t2] * alpha + rs;

        if (__any(alpha != 1.0f)) {
#pragma unroll
          for (int dt = 0; dt < 4; dt++)
#pragma unroll
            for (int r = 0; r < 16; r++) oa[t2][dt][r] *= alpha;
        }
      }

      // ---- O^T += V^T @ P^T  (A-frag V reused across both q-subtiles)
      __builtin_amdgcn_s_setprio(1);
#pragma unroll
      for (int ks = 0; ks < 4; ks++) {
        int c = 2 * ks + hi;
        bf16x8 pf0, pf1;
        {
          int q0l = l31;
          int q1l = 32 + l31;
          pf0 = *(const bf16x8*)&Ps[q0l * 64 + ((c ^ (q0l & 7)) * 8)];
          pf1 = *(const bf16x8*)&Ps[q1l * 64 + ((c ^ (q1l & 7)) * 8)];
        }
#pragma unroll
        for (int dt = 0; dt < 4; dt++) {
          int d = dt * 32 + l31;
          bf16x8 vf = *(const bf16x8*)&Vs[d * 64 + ((c ^ (d & 7)) * 8)];
          oa[0][dt] = __builtin_amdgcn_mfma_f32_32x32x16_bf16(vf, pf0, oa[0][dt], 0, 0, 0);
          oa[1][dt] = __builtin_amdgcn_mfma_f32_32x32x16_bf16(vf, pf1, oa[1][dt], 0, 0, 0);
        }
      }
      __builtin_amdgcn_s_setprio(0);
    }
  }

  // ---- epilogue: normalize, transpose O^T -> O rows via per-wave LDS patch
  __syncthreads();                 // everyone done reading Ks/Vs/Ps
  unsigned short* patch = &S_[w][0];   // [64 q][128 d], chunk-swizzled ^ (q&7)
  float inv[2] = {1.0f / ls[0], 1.0f / ls[1]};
#pragma unroll
  for (int t2 = 0; t2 < 2; t2++) {
    const int qloc = t2 * 32 + l31;
#pragma unroll
    for (int dt = 0; dt < 4; dt++)
#pragma unroll
      for (int rq = 0; rq < 4; rq++) {
        float a0 = oa[t2][dt][rq * 4 + 0] * inv[t2];
        float a1 = oa[t2][dt][rq * 4 + 1] * inv[t2];
        float a2 = oa[t2][dt][rq * 4 + 2] * inv[t2];
        float a3 = oa[t2][dt][rq * 4 + 3] * inv[t2];
        int doff = dt * 32 + 8 * rq + 4 * hi;
        int c = doff >> 3;
        uint2 val = {pack_bf2_rne(a0, a1), pack_bf2_rne(a2, a3)};
        *(uint2*)&patch[qloc * 128 + ((c ^ (qloc & 7)) * 8) + (doff & 7)] = val;
      }
  }
  // in-wave: write -> read dependency handled by compiler waitcnt
#pragma unroll
  for (int it = 0; it < 16; it++) {
    int idx2 = it * 64 + lane;
    int row = idx2 >> 4, c = idx2 & 15;
    int cc = (c & 7) ^ (row & 7);
    int cs = (c & 8) | cc;          // swizzle only low 3 bits (mask was &7)
    ushortx8 vv = *(const ushortx8*)&patch[row * 128 + cs * 8];
    *(ushortx8*)&o[(size_t)(b * SEQ_ + qb + w * 64 + row) * 4096 + h * HD_ + c * 8] = vv;
  }
}

// ---------------------------------------------------------------------------
extern "C" void kernel_launch(void* const* d_in, const int* in_sizes, int n_in,
                              void* d_out, int out_size, void* d_ws, size_t ws_size,
                              hipStream_t stream)
{
  const float* x  = (const float*)d_in[0];
  const float* wq = (const float*)d_in[1];
  const float* wk = (const float*)d_in[2];
  const float* wv = (const float*)d_in[3];
  const float* wo = (const float*)d_in[4];
  const float* fc = (const float*)d_in[5];
  const float* fs = (const float*)d_in[6];
  float* out = (float*)d_out;

  // bf16 workspace layout (2B elems): total 136 MB
  unsigned short* xb    = (unsigned short*)d_ws;                 // 4096x4096 (32MB), reused as ab
  unsigned short* wqkvT = xb    + (size_t)NTOK_ * DIM_;          // 6144x4096 (48MB), reused as woT
  unsigned short* qkvb  = wqkvT + (size_t)QKVW_ * DIM_;          // 4096x6144 (48MB)
  unsigned short* vtb   = qkvb  + (size_t)NTOK_ * QKVW_;         // 8x128x... (8MB)
  unsigned short* ab    = xb;    // alias: xb dead after QKV proj
  unsigned short* woT   = wqkvT; // alias: wqkvT dead after QKV proj

  dim3 blk(256);

  xconv<<<(NTOK_ * DIM_ / 4) / 256, blk, 0, stream>>>(x, xb);
  wtrans<<<dim3(DIM_ / 32, DIM_ / 32), blk, 0, stream>>>(wq, wqkvT, DIM_, DIM_);
  wtrans<<<dim3((NKVH_ * HD_) / 32, DIM_ / 32), blk, 0, stream>>>(wk, wqkvT + (size_t)4096 * DIM_, DIM_, NKVH_ * HD_);
  wtrans<<<dim3((NKVH_ * HD_) / 32, DIM_ / 32), blk, 0, stream>>>(wv, wqkvT + (size_t)5120 * DIM_, DIM_, NKVH_ * HD_);

  // fused QKV projection: [4096 tok][6144] bf16 -- 256x256 tiles, 24x16 = 384 wgs
  gemm_bt8<true><<<dim3((QKVW_ / 256) * (NTOK_ / 256)), dim3(512), 0, stream>>>(
      xb, wqkvT, qkvb, NTOK_, QKVW_, DIM_);

  wtrans<<<dim3(DIM_ / 32, DIM_ / 32), blk, 0, stream>>>(wo, woT, DIM_, DIM_);  // aliases wqkvT: after QKV GEMM

  // RoPE on Q (2048 u32/token) and K (512 u32/token at base 2048)
  rope2<<<(NTOK_ * 2048) / 256, blk, 0, stream>>>((unsigned int*)qkvb, fc, fs, 11, 3072, 0);
  rope2<<<(NTOK_ * 512) / 256, blk, 0, stream>>>((unsigned int*)qkvb, fc, fs, 9, 3072, 2048);

  vtrans2<<<dim3(SEQ_ / 32, HD_ / 32, BSZ_ * NKVH_), blk, 0, stream>>>(qkvb, vtb);

  // flash attention: 1-D LPT-ordered grid (512 blocks)
  flash_attn2<<<dim3((SEQ_ / 256) * NH_ * BSZ_), blk, 0, stream>>>(qkvb, vtb, ab);

  // output projection: 16x16 = 256 wgs (perfectly balanced on 256 CUs)
  gemm_bt8<false><<<dim3((DIM_ / 256) * (NTOK_ / 256)), dim3(512), 0, stream>>>(
      ab, woT, out, NTOK_, DIM_, DIM_);
}

// Round 7
// 703.601 us; speedup vs baseline: 1.1051x; 1.0195x over previous
//
#include <hip/hip_runtime.h>

#define BSZ_  4
#define SEQ_  1024
#define NH_   32
#define NKVH_ 8
#define HD_   128
#define DIM_  4096
#define NTOK_ (BSZ_ * SEQ_)   // 4096 tokens
#define QKVW_ 6144            // fused QKV output width (u16 elems per token)

typedef float  floatx4  __attribute__((ext_vector_type(4)));
typedef float  floatx16 __attribute__((ext_vector_type(16)));
typedef __bf16 bf16x8   __attribute__((ext_vector_type(8)));
typedef unsigned short ushortx8 __attribute__((ext_vector_type(8)));

__device__ __forceinline__ float fast_exp2(float x) {
  return __builtin_amdgcn_exp2f(x);   // v_exp_f32 (computes 2^x natively)
}

__device__ __forceinline__ unsigned short f2bf_bits(float f) {
  unsigned int u = __float_as_uint(f);
  u += 0x7FFFu + ((u >> 16) & 1u);   // round-to-nearest-even
  return (unsigned short)(u >> 16);
}
__device__ __forceinline__ unsigned int pack_bf2_rne(float lo, float hi_) {
  return (unsigned int)f2bf_bits(lo) | ((unsigned int)f2bf_bits(hi_) << 16);
}
// truncating pack of two fp32 -> bf16x2 (one v_perm_b32)
__device__ __forceinline__ unsigned int pack_bf2_trunc(float lo, float hi_) {
  return __builtin_amdgcn_perm(__float_as_uint(hi_), __float_as_uint(lo), 0x07060302u);
}

// async global->LDS, 16B per lane; LDS dest = wave-uniform base + lane*16
__device__ __forceinline__ void gld16(const void* g, void* l) {
  __builtin_amdgcn_global_load_lds(
      (const __attribute__((address_space(1))) void*)g,
      (__attribute__((address_space(3))) void*)l, 16, 0, 0);
}

// ---------------------------------------------------------------------------
// fp32 -> bf16 convert (contiguous).
// ---------------------------------------------------------------------------
__global__ __launch_bounds__(256)
void xconv(const float* __restrict__ X, unsigned short* __restrict__ XB)
{
  size_t i = ((size_t)blockIdx.x * 256 + threadIdx.x) * 4;
  float4 v = *(const float4*)&X[i];
  ushort4 o;
  o.x = f2bf_bits(v.x); o.y = f2bf_bits(v.y);
  o.z = f2bf_bits(v.z); o.w = f2bf_bits(v.w);
  *(ushort4*)&XB[i] = o;
}

// ---------------------------------------------------------------------------
// Weight transpose-convert: W[K][N] fp32 -> WT[N][K] bf16. 32x32 tiles.
// ---------------------------------------------------------------------------
__global__ __launch_bounds__(256)
void wtrans(const float* __restrict__ W, unsigned short* __restrict__ WT,
            int K, int N)
{
  __shared__ unsigned short T[32][36];
  const int k0 = blockIdx.y * 32, n0 = blockIdx.x * 32;
  const int t = threadIdx.x;
  {
    int kr = t >> 3, nc = (t & 7) * 4;
    float4 v = *(const float4*)&W[(size_t)(k0 + kr) * N + n0 + nc];
    T[kr][nc + 0] = f2bf_bits(v.x);
    T[kr][nc + 1] = f2bf_bits(v.y);
    T[kr][nc + 2] = f2bf_bits(v.z);
    T[kr][nc + 3] = f2bf_bits(v.w);
  }
  __syncthreads();
  {
    int nr = t >> 3, kc = (t & 7) * 4;
    ushort4 o;
    o.x = T[kc + 0][nr]; o.y = T[kc + 1][nr];
    o.z = T[kc + 2][nr]; o.w = T[kc + 3][nr];
    *(ushort4*)&WT[(size_t)(n0 + nr) * K + k0 + kc] = o;
  }
}

// ---------------------------------------------------------------------------
// V transpose from fused qkv buffer: qkv[tok][5120 + kvh*128 + d] ->
// VT[(b*8+kvh)*128 + d][1024 s]. 32x32 tiles. grid = (SEQ/32, HD/32, B*NKVH)
// ---------------------------------------------------------------------------
__global__ __launch_bounds__(256)
void vtrans2(const unsigned short* __restrict__ qkv, unsigned short* __restrict__ VT)
{
  __shared__ unsigned short T[32][36];
  const int bh = blockIdx.z;                 // b*8+kvh
  const int s0 = blockIdx.x * 32, d0 = blockIdx.y * 32;
  const int b = bh >> 3, kvh = bh & 7;
  const int t = threadIdx.x;
  {
    int sr = t >> 3, dc = (t & 7) * 4;
    ushort4 v = *(const ushort4*)&qkv[(size_t)(b * SEQ_ + s0 + sr) * QKVW_ + 5120 + kvh * HD_ + d0 + dc];
    T[sr][dc + 0] = v.x; T[sr][dc + 1] = v.y;
    T[sr][dc + 2] = v.z; T[sr][dc + 3] = v.w;
  }
  __syncthreads();
  {
    int dr = t >> 3, sc = (t & 7) * 4;
    ushort4 o;
    o.x = T[sc + 0][dr]; o.y = T[sc + 1][dr];
    o.z = T[sc + 2][dr]; o.w = T[sc + 3][dr];
    *(ushort4*)&VT[((size_t)bh * HD_ + d0 + dr) * SEQ_ + s0 + sc] = o;
  }
}

// ---------------------------------------------------------------------------
// RoPE in place on bf16 pairs inside the fused qkv buffer.
// ---------------------------------------------------------------------------
__global__ __launch_bounds__(256)
void rope2(unsigned int* __restrict__ t, const float* __restrict__ cosf,
           const float* __restrict__ sinf, int shift, int stride_u32, int base_u32)
{
  int idx = blockIdx.x * 256 + threadIdx.x;
  int tok = idx >> shift;
  int rem = idx & ((1 << shift) - 1);
  int d2  = idx & 63;
  int pos = tok & (SEQ_ - 1);
  unsigned int* p = &t[(size_t)tok * stride_u32 + base_u32 + rem];
  unsigned int pv = *p;
  float xe = __uint_as_float(pv << 16);
  float xo = __uint_as_float(pv & 0xFFFF0000u);
  float cv = cosf[pos * 64 + d2];
  float sv = sinf[pos * 64 + d2];
  float oe = xe * cv - xo * sv;
  float oo = xe * sv + xo * cv;
  *p = pack_bf2_rne(oe, oo);
}

// ---------------------------------------------------------------------------
// GEMM w16: 256x256x32 tile, 16 waves (1024 thr, 4M x 4N), per-wave 64x64.
// C = A @ B^T (B stored [N][K]), bf16 in, bf16/fp32 out.
//
// Why 16 waves: forces 4 waves/SIMD co-resident (vs 2 before) -> the MFMA
// pipe stays fed across ds_read/barrier skew. Per-wave acc = 4x4 floatx4
// (64 regs) so the 128-reg cap at 4 waves/EU holds (~116 est).
//
// LDS: 4-deep ring x [256][32] per operand = 128 KiB, 1 block/CU.
// ONE barrier per K-tile:
//   { ds_read 8 frags(t) | stage(t+3): 1 A + 1 B gld16 (block-wide 16KB each)
//     | setprio(1) 16 MFMA setprio(0) | s_waitcnt vmcnt(4) | s_barrier }
// Ring-4 proof: stage target buf (t+3)&3 == (t-1)&3, readers sealed by the
// end-of-(t-1) barrier which precedes this iteration's stage in every wave's
// program order. vmcnt(4) leaves exactly tiles t+2,t+3 (4 loads) in flight
// -> tile t+1 landed chip-wide before any post-barrier ds_read.
// Tail: pk clamps to 0 -> dummy stage into dead buffer keeps counts uniform;
// single vmcnt(0) after the loop.
// T2 chunk-XOR swizzle (c ^= (row>>1)&3) both-sides; T1 XCD swizzle.
// ---------------------------------------------------------------------------
template<bool OUT_BF16>
__global__ __launch_bounds__(1024, 4)
void gemm_w16(const unsigned short* __restrict__ A,   // [M][K] bf16
              const unsigned short* __restrict__ B,   // [N][K] bf16
              void* __restrict__ Cout, int M, int N, int K)
{
  __shared__ __align__(16) unsigned short As[4][256][32];
  __shared__ __align__(16) unsigned short Bs[4][256][32];

  const int tid  = threadIdx.x;
  const int w    = tid >> 6;      // 0..15
  const int lane = tid & 63;
  const int l16  = lane & 15;
  const int quad = lane >> 4;
  const int wr   = w >> 2;        // 0..3  (M)
  const int wc   = w & 3;         // 0..3  (N)

  // T1: XCD-aware swizzle (gridDim.x % 8 == 0 at both call sites)
  int wg = blockIdx.x;
  const int q8 = gridDim.x >> 3;
  wg = (wg & 7) * q8 + (wg >> 3);
  const int nbx = N >> 8;
  const int bm = (wg / nbx) * 256;
  const int bn = (wg % nbx) * 256;

  // staging: thread -> row tid>>2 (0..255), chunk tid&3; one block-wide
  // gld16 covers a full 256x32 operand tile (1024 lanes x 16B = 16 KiB).
  // Source chunk pre-swizzled so LDS stays linear.
  const int srow = tid >> 2;
  const int scs  = (tid & 3) ^ ((srow >> 1) & 3);
  const unsigned short* Ag = &A[(size_t)(bm + srow) * K + scs * 8];
  const unsigned short* Bg = &B[(size_t)(bn + srow) * K + scs * 8];
  char* AsW = (char*)&As[0][0][0] + w * 1024;   // + buf*16384
  char* BsW = (char*)&Bs[0][0][0] + w * 1024;

  const int ntiles = K >> 5;   // 128 for K=4096

  auto stage = [&](int kt, int buf) {
    size_t ko = (size_t)kt << 5;
    gld16(Ag + ko, AsW + buf * 16384);
    gld16(Bg + ko, BsW + buf * 16384);
  };

  floatx4 acc[4][4];
#pragma unroll
  for (int i = 0; i < 4; i++)
#pragma unroll
    for (int j = 0; j < 4; j++) acc[i][j] = (floatx4){0.f, 0.f, 0.f, 0.f};

  // fragment-read swizzle: row = 64*wr|wc + 16*i + l16 -> (row>>1)&3 = (l16>>1)&3
  const int cfr = quad ^ ((l16 >> 1) & 3);
  const unsigned short* ArF = &As[0][wr * 64][cfr * 8];   // + buf*8192elem + i*16*32 + l16*32
  const unsigned short* BrF = &Bs[0][wc * 64][cfr * 8];

  // ---- prologue: stage tiles 0,1,2 (6 loads/wave); tile 0 landed at vmcnt(4)
  stage(0, 0); stage(1, 1); stage(2, 2);
  asm volatile("s_waitcnt vmcnt(4)" ::: "memory");
  __builtin_amdgcn_s_barrier();

#pragma unroll 1
  for (int t = 0; t < ntiles; t++) {
    const int buf = t & 3;

    // ---- ds_read this tile's fragments (compiler inserts lgkm waits)
    bf16x8 af[4], bfr[4];
    {
      const unsigned short* Ab = ArF + (size_t)buf * (256 * 32) + l16 * 32;
      const unsigned short* Bb = BrF + (size_t)buf * (256 * 32) + l16 * 32;
#pragma unroll
      for (int i = 0; i < 4; i++) af[i]  = *(const bf16x8*)&Ab[i * (16 * 32)];
#pragma unroll
      for (int j = 0; j < 4; j++) bfr[j] = *(const bf16x8*)&Bb[j * (16 * 32)];
    }

    // ---- issue stage of tile t+3 (clamped dummy at tail; target buf dead)
    {
      int pk = (t + 3 < ntiles) ? t + 3 : 0;
      stage(pk, (t + 3) & 3);
    }

    __builtin_amdgcn_s_setprio(1);
#pragma unroll
    for (int i = 0; i < 4; i++)
#pragma unroll
      for (int j = 0; j < 4; j++)
        acc[i][j] = __builtin_amdgcn_mfma_f32_16x16x32_bf16(af[i], bfr[j], acc[i][j], 0, 0, 0);
    __builtin_amdgcn_s_setprio(0);

    // tile t+1 landed (only t+2,t+3's 4 loads remain), then release buffers
    asm volatile("s_waitcnt vmcnt(4)" ::: "memory");
    __builtin_amdgcn_s_barrier();
  }

  asm volatile("s_waitcnt vmcnt(0)" ::: "memory");   // drain dummy tail stages

  // ---- epilogue: C write
#pragma unroll
  for (int i = 0; i < 4; i++)
#pragma unroll
    for (int j = 0; j < 4; j++)
#pragma unroll
      for (int r = 0; r < 4; r++) {
        size_t row = bm + wr * 64 + i * 16 + quad * 4 + r;
        size_t col = bn + wc * 64 + j * 16 + l16;
        if (OUT_BF16)
          ((unsigned short*)Cout)[row * N + col] = f2bf_bits(acc[i][j][r]);
        else
          ((float*)Cout)[row * N + col] = acc[i][j][r];
      }
}

// ---------------------------------------------------------------------------
// Flash attention v2 (GQA, causal): S^T = K Q^T via mfma_32x32x16 so softmax
// is per-lane-column; O^T = V^T P^T. All LDS XOR-chunk-swizzled (conflict-free).
// Block = 256 q of one (b,h); 4 waves x 64 q; K-tiles of 64 keys.
// (R6 state: T14 async-STAGE, T13 defer-max, LPT grid pairing, T5 setprio.)
// ---------------------------------------------------------------------------
__global__ __launch_bounds__(256, 2)
void flash_attn2(const unsigned short* __restrict__ qkv,
                 const unsigned short* __restrict__ vt,
                 unsigned short* __restrict__ o)
{
  __shared__ __align__(16) unsigned short S_[4][8192];  // 64 KiB total
  unsigned short* Ks = &S_[0][0];            // [64 key][128 d], chunk-swizzled ^ (key&15)
  unsigned short* Vs = &S_[1][0];            // [128 d][64 key], chunk-swizzled ^ (d&7)
  // Ps per wave: S_[2..3], 4096 u16 each:   [64 q][64 key], chunk-swizzled ^ (q&7)

  // ---- LPT remap: grp 0->qt3, 1->qt2, 2->qt0, 3->qt1
  const int bid = blockIdx.x;
  const int grp = bid >> 7;
  const int idx = bid & 127;
  const int qt = (grp == 0) ? 3 : (grp == 1) ? 2 : (grp == 2) ? 0 : 1;
  const int h = idx & 31, b = idx >> 5;

  const int kvh = h >> 2;
  const int tid = threadIdx.x, w = tid >> 6, lane = tid & 63;
  const int l31 = lane & 31, hi = lane >> 5;
  const int qb = qt * 256, qw = qb + w * 64;
  unsigned short* Ps = &S_[2][0] + w * 4096;

  const float CEXP = (float)(0.08838834764831845 * 1.4426950408889634); // scale*log2(e)

  // ---- Q fragments in registers (B-operand layout: n=l31, k=hi*8+j per 16-k step)
  bf16x8 qf[2][8];
#pragma unroll
  for (int t2 = 0; t2 < 2; t2++) {
    const unsigned short* qrow =
        &qkv[(size_t)(b * SEQ_ + qw + t2 * 32 + l31) * QKVW_ + h * HD_ + hi * 8];
#pragma unroll
    for (int s = 0; s < 8; s++)
      qf[t2][s] = *(const bf16x8*)&qrow[s * 16];
  }

  floatx16 oa[2][4];   // O^T accumulators: [q-subtile][d-tile], col=q=l31
#pragma unroll
  for (int t2 = 0; t2 < 2; t2++)
#pragma unroll
    for (int dt = 0; dt < 4; dt++)
#pragma unroll
      for (int r = 0; r < 16; r++) oa[t2][dt][r] = 0.f;

  float ms[2] = {-3.0e38f, -3.0e38f};  // running max, SCALED (log2) units
  float ls[2] = {0.f, 0.f};

  const int nk = qb + 256;
  const int qmaxw = qw + 63;

  // ---- T14 staging state: next tile's K/V in registers (32 VGPR)
  ushortx8 kreg[4], vreg[4];
  const size_t kg0 = (size_t)(b * SEQ_) * QKVW_ + 4096 + kvh * HD_;
  const size_t vg0 = ((size_t)(b * NKVH_ + kvh) * HD_) * SEQ_;
  const int krow = tid >> 4, kc = tid & 15;        // K: covers 16 keys/iter
  const int vrow = tid >> 3, vc = tid & 7;         // V: covers 32 d/iter

  auto issue_loads = [&](int kb) {
    const size_t gb = kg0 + (size_t)kb * QKVW_;
#pragma unroll
    for (int it = 0; it < 4; it++)
      kreg[it] = *(const ushortx8*)&qkv[gb + (size_t)(it * 16 + krow) * QKVW_ + kc * 8];
    const size_t vb = vg0 + kb;
#pragma unroll
    for (int it = 0; it < 4; it++)
      vreg[it] = *(const ushortx8*)&vt[vb + (size_t)(it * 32 + vrow) * SEQ_ + vc * 8];
  };
  auto write_lds = [&]() {
#pragma unroll
    for (int it = 0; it < 4; it++) {
      int key = it * 16 + krow;
      *(ushortx8*)&Ks[key * 128 + ((kc ^ (key & 15)) * 8)] = kreg[it];
    }
#pragma unroll
    for (int it = 0; it < 4; it++) {
      int d = it * 32 + vrow;
      *(ushortx8*)&Vs[d * 64 + ((vc ^ (d & 7)) * 8)] = vreg[it];
    }
  };

  issue_loads(0);

  for (int kb_ = 0; kb_ < nk; kb_ += 64) {
    __syncthreads();   // WAR: all readers of previous tile done (drains vmcnt
                       // for the prefetch we are about to consume -- desired)
    write_lds();
    if (kb_ + 64 < nk) issue_loads(kb_ + 64);   // prefetch under compute
    asm volatile("s_waitcnt lgkmcnt(0)" ::: "memory");   // ds_writes visible
    __builtin_amdgcn_s_barrier();                        // loads stay in flight

    if (kb_ <= qmaxw) {                      // wave has >=1 unmasked key in tile
      const bool needmask = (kb_ + 63 > qw);

#pragma unroll
      for (int t2 = 0; t2 < 2; t2++) {
        // ---- S^T = K @ Q^T : two 32-key C-tiles, rows=keys, cols=queries
        floatx16 sc[2];
#pragma unroll
        for (int r = 0; r < 16; r++) { sc[0][r] = 0.f; sc[1][r] = 0.f; }
        __builtin_amdgcn_s_setprio(1);
#pragma unroll
        for (int s = 0; s < 8; s++) {
          int c = 2 * s + hi;
          bf16x8 k0 = *(const bf16x8*)&Ks[l31 * 128 + ((c ^ (l31 & 15)) * 8)];
          bf16x8 k1 = *(const bf16x8*)&Ks[(32 + l31) * 128 + ((c ^ ((32 + l31) & 15)) * 8)];
          sc[0] = __builtin_amdgcn_mfma_f32_32x32x16_bf16(k0, qf[t2][s], sc[0], 0, 0, 0);
          sc[1] = __builtin_amdgcn_mfma_f32_32x32x16_bf16(k1, qf[t2][s], sc[1], 0, 0, 0);
        }
        __builtin_amdgcn_s_setprio(0);

        // ---- causal mask (row = key = (r&3)+8*(r>>2)+4*hi; col = q = l31)
        if (needmask) {
          const int q = qw + t2 * 32 + l31;
#pragma unroll
          for (int k2 = 0; k2 < 2; k2++)
#pragma unroll
            for (int r = 0; r < 16; r++) {
              int key = kb_ + k2 * 32 + (r & 3) + 8 * (r >> 2) + 4 * hi;
              if (key > q) sc[k2][r] = -3.0e38f;
            }
        }

        // ---- online softmax for this lane's query (32 vals in-lane + xor32)
        float mx0 = sc[0][0], mx1 = sc[0][1];
#pragma unroll
        for (int r = 2; r < 16; r += 2) { mx0 = fmaxf(mx0, sc[0][r]); mx1 = fmaxf(mx1, sc[0][r + 1]); }
#pragma unroll
        for (int r = 0; r < 16; r += 2) { mx0 = fmaxf(mx0, sc[1][r]); mx1 = fmaxf(mx1, sc[1][r + 1]); }
        float mx = fmaxf(mx0, mx1);
        mx = fmaxf(mx, __shfl_xor(mx, 32));
        float mxs = mx * CEXP;

        // ---- T13 defer-max: keep old max unless growth > 8 (P <= 2^8)
        float mn, alpha;
        if (__all(mxs - ms[t2] <= 8.0f)) {
          mn = ms[t2]; alpha = 1.0f;
        } else {
          mn = fmaxf(ms[t2], mxs);
          alpha = fast_exp2(ms[t2] - mn);
          ms[t2] = mn;
        }

        float rs0 = 0.f, rs1 = 0.f;
        const int qloc = t2 * 32 + l31;
#pragma unroll
        for (int k2 = 0; k2 < 2; k2++) {
          unsigned int pk[8];
#pragma unroll
          for (int r = 0; r < 16; r += 2) {
            float p0 = fast_exp2(__builtin_fmaf(sc[k2][r],     CEXP, -mn));
            float p1 = fast_exp2(__builtin_fmaf(sc[k2][r + 1], CEXP, -mn));
            rs0 += p0; rs1 += p1;
            pk[r >> 1] = pack_bf2_trunc(p0, p1);
          }
#pragma unroll
          for (int rq = 0; rq < 4; rq++) {
            int keyoff = k2 * 32 + 8 * rq + 4 * hi;
            int c = keyoff >> 3;
            uint2 val = {pk[rq * 2], pk[rq * 2 + 1]};
            *(uint2*)&Ps[qloc * 64 + ((c ^ (qloc & 7)) * 8) + (keyoff & 7)] = val;
          }
        }
        float rs = rs0 + rs1;
        rs += __shfl_xor(rs, 32);
        ls[t2] = ls[t2] * alpha + rs;

        if (__any(alpha != 1.0f)) {
#pragma unroll
          for (int dt = 0; dt < 4; dt++)
#pragma unroll
            for (int r = 0; r < 16; r++) oa[t2][dt][r] *= alpha;
        }
      }

      // ---- O^T += V^T @ P^T  (A-frag V reused across both q-subtiles)
      __builtin_amdgcn_s_setprio(1);
#pragma unroll
      for (int ks = 0; ks < 4; ks++) {
        int c = 2 * ks + hi;
        bf16x8 pf0, pf1;
        {
          int q0l = l31;
          int q1l = 32 + l31;
          pf0 = *(const bf16x8*)&Ps[q0l * 64 + ((c ^ (q0l & 7)) * 8)];
          pf1 = *(const bf16x8*)&Ps[q1l * 64 + ((c ^ (q1l & 7)) * 8)];
        }
#pragma unroll
        for (int dt = 0; dt < 4; dt++) {
          int d = dt * 32 + l31;
          bf16x8 vf = *(const bf16x8*)&Vs[d * 64 + ((c ^ (d & 7)) * 8)];
          oa[0][dt] = __builtin_amdgcn_mfma_f32_32x32x16_bf16(vf, pf0, oa[0][dt], 0, 0, 0);
          oa[1][dt] = __builtin_amdgcn_mfma_f32_32x32x16_bf16(vf, pf1, oa[1][dt], 0, 0, 0);
        }
      }
      __builtin_amdgcn_s_setprio(0);
    }
  }

  // ---- epilogue: normalize, transpose O^T -> O rows via per-wave LDS patch
  __syncthreads();                 // everyone done reading Ks/Vs/Ps
  unsigned short* patch = &S_[w][0];   // [64 q][128 d], chunk-swizzled ^ (q&7)
  float inv[2] = {1.0f / ls[0], 1.0f / ls[1]};
#pragma unroll
  for (int t2 = 0; t2 < 2; t2++) {
    const int qloc = t2 * 32 + l31;
#pragma unroll
    for (int dt = 0; dt < 4; dt++)
#pragma unroll
      for (int rq = 0; rq < 4; rq++) {
        float a0 = oa[t2][dt][rq * 4 + 0] * inv[t2];
        float a1 = oa[t2][dt][rq * 4 + 1] * inv[t2];
        float a2 = oa[t2][dt][rq * 4 + 2] * inv[t2];
        float a3 = oa[t2][dt][rq * 4 + 3] * inv[t2];
        int doff = dt * 32 + 8 * rq + 4 * hi;
        int c = doff >> 3;
        uint2 val = {pack_bf2_rne(a0, a1), pack_bf2_rne(a2, a3)};
        *(uint2*)&patch[qloc * 128 + ((c ^ (qloc & 7)) * 8) + (doff & 7)] = val;
      }
  }
  // in-wave: write -> read dependency handled by compiler waitcnt
#pragma unroll
  for (int it = 0; it < 16; it++) {
    int idx2 = it * 64 + lane;
    int row = idx2 >> 4, c = idx2 & 15;
    int cc = (c & 7) ^ (row & 7);
    int cs = (c & 8) | cc;          // swizzle only low 3 bits (mask was &7)
    ushortx8 vv = *(const ushortx8*)&patch[row * 128 + cs * 8];
    *(ushortx8*)&o[(size_t)(b * SEQ_ + qb + w * 64 + row) * 4096 + h * HD_ + c * 8] = vv;
  }
}

// ---------------------------------------------------------------------------
extern "C" void kernel_launch(void* const* d_in, const int* in_sizes, int n_in,
                              void* d_out, int out_size, void* d_ws, size_t ws_size,
                              hipStream_t stream)
{
  const float* x  = (const float*)d_in[0];
  const float* wq = (const float*)d_in[1];
  const float* wk = (const float*)d_in[2];
  const float* wv = (const float*)d_in[3];
  const float* wo = (const float*)d_in[4];
  const float* fc = (const float*)d_in[5];
  const float* fs = (const float*)d_in[6];
  float* out = (float*)d_out;

  // bf16 workspace layout (2B elems): total 136 MB
  unsigned short* xb    = (unsigned short*)d_ws;                 // 4096x4096 (32MB), reused as ab
  unsigned short* wqkvT = xb    + (size_t)NTOK_ * DIM_;          // 6144x4096 (48MB), reused as woT
  unsigned short* qkvb  = wqkvT + (size_t)QKVW_ * DIM_;          // 4096x6144 (48MB)
  unsigned short* vtb   = qkvb  + (size_t)NTOK_ * QKVW_;         // 8x128x... (8MB)
  unsigned short* ab    = xb;    // alias: xb dead after QKV proj
  unsigned short* woT   = wqkvT; // alias: wqkvT dead after QKV proj

  dim3 blk(256);

  xconv<<<(NTOK_ * DIM_ / 4) / 256, blk, 0, stream>>>(x, xb);
  wtrans<<<dim3(DIM_ / 32, DIM_ / 32), blk, 0, stream>>>(wq, wqkvT, DIM_, DIM_);
  wtrans<<<dim3((NKVH_ * HD_) / 32, DIM_ / 32), blk, 0, stream>>>(wk, wqkvT + (size_t)4096 * DIM_, DIM_, NKVH_ * HD_);
  wtrans<<<dim3((NKVH_ * HD_) / 32, DIM_ / 32), blk, 0, stream>>>(wv, wqkvT + (size_t)5120 * DIM_, DIM_, NKVH_ * HD_);

  // fused QKV projection: [4096 tok][6144] bf16 -- 256x256 tiles, 24x16 = 384 wgs
  gemm_w16<true><<<dim3((QKVW_ / 256) * (NTOK_ / 256)), dim3(1024), 0, stream>>>(
      xb, wqkvT, qkvb, NTOK_, QKVW_, DIM_);

  wtrans<<<dim3(DIM_ / 32, DIM_ / 32), blk, 0, stream>>>(wo, woT, DIM_, DIM_);  // aliases wqkvT: after QKV GEMM

  // RoPE on Q (2048 u32/token) and K (512 u32/token at base 2048)
  rope2<<<(NTOK_ * 2048) / 256, blk, 0, stream>>>((unsigned int*)qkvb, fc, fs, 11, 3072, 0);
  rope2<<<(NTOK_ * 512) / 256, blk, 0, stream>>>((unsigned int*)qkvb, fc, fs, 9, 3072, 2048);

  vtrans2<<<dim3(SEQ_ / 32, HD_ / 32, BSZ_ * NKVH_), blk, 0, stream>>>(qkvb, vtb);

  // flash attention: 1-D LPT-ordered grid (512 blocks)
  flash_attn2<<<dim3((SEQ_ / 256) * NH_ * BSZ_), blk, 0, stream>>>(qkvb, vtb, ab);

  // output projection: 256x256 tiles, 16x16 = 256 wgs (perfect packing)
  gemm_w16<false><<<dim3((DIM_ / 256) * (NTOK_ / 256)), dim3(1024), 0, stream>>>(
      ab, woT, out, NTOK_, DIM_, DIM_);
}